// Round 14
// baseline (370.445 us; speedup 1.0000x reference)
//
#include <hip/hip_runtime.h>
#include <hip/hip_bf16.h>
#include <stdint.h>

// ---------- common types / helpers ----------
typedef __attribute__((ext_vector_type(8))) short short8;   // 8 bf16 = 4 VGPR (MFMA A/B frag)
typedef __attribute__((ext_vector_type(4))) float f32x4;    // MFMA C/D frag
typedef __attribute__((ext_vector_type(4))) float f4;
typedef __attribute__((ext_vector_type(4))) short s4;

typedef __attribute__((address_space(1))) const void gvoid_t;
typedef __attribute__((address_space(3))) void lvoid_t;

__device__ __forceinline__ void gload_lds16(const void* g, void* l) {
  __builtin_amdgcn_global_load_lds((gvoid_t*)g, (lvoid_t*)l, 16, 0, 0);
}

__device__ __forceinline__ ushort f2b(float f) {  // f32 -> bf16 RNE
  union { float f; uint32_t u; } v; v.f = f;
  return (ushort)((v.u + 0x7fffu + ((v.u >> 16) & 1u)) >> 16);
}
__device__ __forceinline__ float b2f(ushort b) {
  union { uint32_t u; float f; } v; v.u = ((uint32_t)b) << 16;
  return v.f;
}

template <int N> __device__ __forceinline__ void wait_vmcnt();
template <> __device__ __forceinline__ void wait_vmcnt<0>() { asm volatile("s_waitcnt vmcnt(0)" ::: "memory"); }

__device__ __forceinline__ void wait_lgkm0() {
  asm volatile("s_waitcnt lgkmcnt(0)" ::: "memory");
  __builtin_amdgcn_sched_barrier(0);   // rule #18: keep MFMA below the wait
}
__device__ __forceinline__ void barrier_fence() {
  asm volatile("s_barrier" ::: "memory");
}

// ---------- prep: f32->bf16 casts + rope cos/sin table (one launch) ----------
__global__ void prep_kernel(const float* __restrict__ x, const float* __restrict__ wq,
                            const float* __restrict__ wo,
                            ushort* __restrict__ Xb, ushort* __restrict__ Wq,
                            ushort* __restrict__ Wo, float2* __restrict__ tab) {
  int b = blockIdx.x, tid = threadIdx.x;
  const float* in; ushort* out; int i;
  if (b < 12288)      { in = x;  out = Xb; i = b * 256 + tid; }
  else if (b < 15744) { in = wq; out = Wq; i = (b - 12288) * 256 + tid; }
  else if (b < 18048) { in = wo; out = Wo; i = (b - 15744) * 256 + tid; }
  else {
    int pos = tid >> 4, fi = tid & 15;
    float inv_freq = __expf(-(float)fi * 0.5756462732485115f);  // ln(10000)/16
    float ang = (float)pos * inv_freq;
    float sn, c;
    __sincosf(ang, &sn, &c);
    tab[tid] = make_float2(c, sn);
    return;
  }
  f4 v = ((const f4*)in)[i];
  s4 o;
  o.x = (short)f2b(v.x); o.y = (short)f2b(v.y);
  o.z = (short)f2b(v.z); o.w = (short)f2b(v.w);
  ((s4*)out)[i] = o;
}

// ---------- gemm11: 4 waves x (128 x BN/2) wave-tiles (LDS-read traffic -35%) ----------
// C[M,N] = A[M,K] @ B[N,K]^T, BM=256, 256 threads. Same 2-ks-phase loop, XOR
// swizzle, XCD-owned bm, 1 vmcnt(0)+barrier per tile as gemm6 (best measured).
// Wave-tile 128xRB: per-phase reads = 8 A + NF B frags; each read feeds 2x the
// MFMAs of the 8-wave version -> LDS pipe load drops 208->136|112 reads/tile.
template <int BN, int KC, typename OutT>
__global__ __launch_bounds__(256, 1) void gemm11(const ushort* __restrict__ A,
                                                 const ushort* __restrict__ B,
                                                 OutT* __restrict__ C) {
  constexpr int NF = BN / 32;            // 9 | 6 n-frags per wave
  constexpr int RB = BN / 2;             // 144 | 96
  constexpr int ABUF = 256 * 64;
  constexpr int BBUF = BN * 64;
  constexpr uint ABYTE = ABUF * 2;       // 32768
  constexpr uint BBYTE = BBUF * 2;       // 36864 | 24576
  constexpr int ARND = 8;                // A stage rounds (32 rows each)
  constexpr int BRND = BN / 32;          // B stage rounds: 9 | 6 (exact)
  constexpr int NT = KC >> 6;

  __shared__ ushort As[2 * ABUF];
  __shared__ ushort Bs[2 * BBUF];

  const int tid = threadIdx.x;
  const int l = tid & 63, w = tid >> 6;      // 4 waves
  const int wr = w >> 1, wc = w & 1;         // 2M x 2N
  const int r16 = l & 15, kh = l >> 4;
  const int sc = (l & 7) ^ (l >> 3);         // pre-swizzled stage source chunk
  const int srow = w * 8 + (l >> 3);         // stage row within a 32-row round

  const int xcd = blockIdx.x & 7;
  const int ii = blockIdx.x >> 3;
  const int bm = xcd * 4 + (ii & 3);         // XCD owns 4 contiguous A panels
  const int bn = ii >> 2;
  const ushort* Ag = A + (size_t)bm * 256 * KC;
  const ushort* Bg = B + (size_t)bn * BN * KC;

  const char* AsR = (const char*)As;
  const char* BsR = (const char*)Bs;
  const uint khsw = ((uint)kh * 16) ^ ((uint)(r16 & 7) * 16);
  const uint PA = (uint)(wr * 128 + r16) * 128 + khsw;
  const uint PB = (uint)(wc * RB + r16) * 128 + khsw;

  // persistent stage bases (advance +64 per K-tile); per-round offset i*32*KC
  const ushort* gA = Ag + (size_t)srow * KC + sc * 8;
  const ushort* gB = Bg + (size_t)srow * KC + sc * 8;

  // prologue: stage tile 0 into buf0
#pragma unroll
  for (int i = 0; i < ARND; ++i) gload_lds16(gA + (size_t)(i * 32) * KC, As + i * 2048 + w * 512);
#pragma unroll
  for (int i = 0; i < BRND; ++i) gload_lds16(gB + (size_t)(i * 32) * KC, Bs + i * 2048 + w * 512);
  gA += 64; gB += 64;
  wait_vmcnt<0>();
  barrier_fence();

  f32x4 acc[8][NF] = {};
  short8 afr[8], bfr[NF];

  for (int u = 0; u < NT; ++u) {
    const int cur = u & 1;
    const uint aoff = cur ? ABYTE : 0u;
    const uint boff = cur ? BBYTE : 0u;
    ushort* An = As + (cur ^ 1) * ABUF;
    ushort* Bn = Bs + (cur ^ 1) * BBUF;
    const bool st = (u + 1 < NT);

    // ===== phase 0 (ks0): reads; stage A(u+1); MFMA
    {
      const uint pa = PA + aoff, pb = PB + boff;
#pragma unroll
      for (int m = 0; m < 8; ++m) afr[m] = *(const short8*)(AsR + pa + m * 2048);
#pragma unroll
      for (int n = 0; n < NF; ++n) bfr[n] = *(const short8*)(BsR + pb + n * 2048);
    }
    if (st) {
#pragma unroll
      for (int i = 0; i < ARND; ++i) gload_lds16(gA + (size_t)(i * 32) * KC, An + i * 2048 + w * 512);
    }
    wait_lgkm0();
    __builtin_amdgcn_s_setprio(1);
#pragma unroll
    for (int m = 0; m < 8; ++m)
#pragma unroll
      for (int n = 0; n < NF; ++n)
        acc[m][n] = __builtin_amdgcn_mfma_f32_16x16x32_bf16(afr[m], bfr[n], acc[m][n], 0, 0, 0);
    __builtin_amdgcn_s_setprio(0);

    // ===== phase 1 (ks1): reads; stage B(u+1); MFMA
    {
      const uint pa = (PA ^ 64u) + aoff, pb = (PB ^ 64u) + boff;
#pragma unroll
      for (int m = 0; m < 8; ++m) afr[m] = *(const short8*)(AsR + pa + m * 2048);
#pragma unroll
      for (int n = 0; n < NF; ++n) bfr[n] = *(const short8*)(BsR + pb + n * 2048);
    }
    if (st) {
#pragma unroll
      for (int i = 0; i < BRND; ++i) gload_lds16(gB + (size_t)(i * 32) * KC, Bn + i * 2048 + w * 512);
    }
    wait_lgkm0();
    __builtin_amdgcn_s_setprio(1);
#pragma unroll
    for (int m = 0; m < 8; ++m)
#pragma unroll
      for (int n = 0; n < NF; ++n)
        acc[m][n] = __builtin_amdgcn_mfma_f32_16x16x32_bf16(afr[m], bfr[n], acc[m][n], 0, 0, 0);
    __builtin_amdgcn_s_setprio(0);

    // ===== boundary
    gA += 64; gB += 64;
    wait_vmcnt<0>();
    barrier_fence();
  }

  // epilogue: D col = lane&15, row = (lane>>4)*4 + reg
  const int rowb = bm * 256 + wr * 128;
  const int colb = bn * BN + wc * RB;
#pragma unroll
  for (int m = 0; m < 8; ++m)
#pragma unroll
    for (int n = 0; n < NF; ++n)
#pragma unroll
      for (int r = 0; r < 4; ++r) {
        int row = rowb + m * 16 + kh * 4 + r;
        int col = colb + n * 16 + r16;
        float val = acc[m][n][r];
        if constexpr (sizeof(OutT) == 2) C[(size_t)row * (BN * 8) + col] = f2b(val);
        else                             C[(size_t)row * (BN * 8) + col] = val;
      }
}

// ---------- in-register Q-rope helper: pair partner is lane^32 (kh^2) ----------
__device__ __forceinline__ short8 shfl_xor32(short8 v) {
  union { short8 s; int i[4]; } a, b;
  a.s = v;
#pragma unroll
  for (int q = 0; q < 4; ++q) b.i[q] = __shfl_xor(a.i[q], 32, 64);
  return b.s;
}
__device__ __forceinline__ short8 rope_frag(short8 v, int pos, int kh, const float2* Tb) {
  short8 p = shfl_xor32(v);
  const float sgn = (kh < 2) ? -1.0f : 1.0f;
  const int ib = pos * 16 + (kh & 1) * 8;
  short8 o;
#pragma unroll
  for (int j = 0; j < 8; ++j) {
    float2 cs = Tb[ib + j];
    o[j] = (short)f2b(b2f((ushort)v[j]) * cs.x + sgn * b2f((ushort)p[j]) * cs.y);
  }
  return o;
}

// ---------- attn3: attention + fused RoPE(Q,K) + fused V-transpose ----------
__global__ __launch_bounds__(512, 1) void attn3_kernel(
    const ushort* __restrict__ QKV,  // [8192][2304] bf16
    const int* __restrict__ mask,    // [32][256]
    const float2* __restrict__ Tab,  // [16][16] float2 (cos,sin)
    ushort* __restrict__ Out) {      // [8192][1536] bf16
  __shared__ ushort Ks[256 * 104];   // roped K, padded stride 104
  __shared__ ushort Vs[96 * 264];    // V^T, padded stride 264
  __shared__ ushort Ps[8][16 * 136];
  __shared__ float Mb[256];
  __shared__ float2 Tb[256];

  const int b = blockIdx.x;
  const int qt = b & 1;
  const int g = (b >> 1) & 3;
  const int bt = b >> 3;
  const int t = threadIdx.x;
  const int l = t & 63, w = t >> 6;
  const int r16 = l & 15, kh = l >> 4;
  const int h = g * 4 + (w >> 1);
  const int qc = w & 1;
  const int t0 = bt & 15;

  if (t < 256) { Tb[t] = Tab[t]; Mb[t] = mask[bt * 256 + t] ? 0.0f : -1.0e9f; }
  __syncthreads();

  // ---- stage K with rope
  {
    const int r = t >> 1, ch = t & 1;
    const ushort* src = QKV + (size_t)(bt * 256 + r) * 2304 + 1536 + g * 96;
    const int p1 = r >> 4, p2 = r & 15;
    if (ch == 0) {
      short8 v0 = *(const short8*)(src + 0);
      short8 v1 = *(const short8*)(src + 8);
      short8 v2 = *(const short8*)(src + 16);
      short8 v3 = *(const short8*)(src + 24);
      short8 o0, o1, o2, o3;
#pragma unroll
      for (int j = 0; j < 8; ++j) {
        float2 ca = Tb[t0 * 16 + j], cb = Tb[t0 * 16 + 8 + j];
        float x1a = b2f((ushort)v0[j]), x2a = b2f((ushort)v2[j]);
        float x1b = b2f((ushort)v1[j]), x2b = b2f((ushort)v3[j]);
        o0[j] = (short)f2b(x1a * ca.x - x2a * ca.y);
        o1[j] = (short)f2b(x1b * cb.x - x2b * cb.y);
        o2[j] = (short)f2b(x1a * ca.y + x2a * ca.x);
        o3[j] = (short)f2b(x1b * cb.y + x2b * cb.x);
      }
      *(short8*)(&Ks[r * 104 + 0])  = o0;
      *(short8*)(&Ks[r * 104 + 8])  = o1;
      *(short8*)(&Ks[r * 104 + 16]) = o2;
      *(short8*)(&Ks[r * 104 + 24]) = o3;
      v0 = *(const short8*)(src + 32);
      v1 = *(const short8*)(src + 40);
      v2 = *(const short8*)(src + 48);
      v3 = *(const short8*)(src + 56);
#pragma unroll
      for (int j = 0; j < 8; ++j) {
        float2 ca = Tb[p1 * 16 + j], cb = Tb[p1 * 16 + 8 + j];
        float x1a = b2f((ushort)v0[j]), x2a = b2f((ushort)v2[j]);
        float x1b = b2f((ushort)v1[j]), x2b = b2f((ushort)v3[j]);
        o0[j] = (short)f2b(x1a * ca.x - x2a * ca.y);
        o1[j] = (short)f2b(x1b * cb.x - x2b * cb.y);
        o2[j] = (short)f2b(x1a * ca.y + x2a * ca.x);
        o3[j] = (short)f2b(x1b * cb.y + x2b * cb.x);
      }
      *(short8*)(&Ks[r * 104 + 32]) = o0;
      *(short8*)(&Ks[r * 104 + 40]) = o1;
      *(short8*)(&Ks[r * 104 + 48]) = o2;
      *(short8*)(&Ks[r * 104 + 56]) = o3;
    } else {
      short8 v0 = *(const short8*)(src + 64);
      short8 v1 = *(const short8*)(src + 72);
      short8 v2 = *(const short8*)(src + 80);
      short8 v3 = *(const short8*)(src + 88);
      short8 o0, o1, o2, o3;
#pragma unroll
      for (int j = 0; j < 8; ++j) {
        float2 ca = Tb[p2 * 16 + j], cb = Tb[p2 * 16 + 8 + j];
        float x1a = b2f((ushort)v0[j]), x2a = b2f((ushort)v2[j]);
        float x1b = b2f((ushort)v1[j]), x2b = b2f((ushort)v3[j]);
        o0[j] = (short)f2b(x1a * ca.x - x2a * ca.y);
        o1[j] = (short)f2b(x1b * cb.x - x2b * cb.y);
        o2[j] = (short)f2b(x1a * ca.y + x2a * ca.x);
        o3[j] = (short)f2b(x1b * cb.y + x2b * cb.x);
      }
      *(short8*)(&Ks[r * 104 + 64]) = o0;
      *(short8*)(&Ks[r * 104 + 72]) = o1;
      *(short8*)(&Ks[r * 104 + 80]) = o2;
      *(short8*)(&Ks[r * 104 + 88]) = o3;
    }
  }

  // ---- stage V transposed
#pragma unroll
  for (int i = 0; i < 6; ++i) {
    int c = t + i * 512;
    int s = c / 12, dq = c - s * 12;
    short8 vv = *(const short8*)(QKV + (size_t)(bt * 256 + s) * 2304 + 1920 + g * 96 + dq * 8);
#pragma unroll
    for (int j = 0; j < 8; ++j)
      Vs[(dq * 8 + j) * 264 + s] = (ushort)vv[j];
  }
  __syncthreads();

  const ushort* Qp = QKV + (size_t)(bt * 256 + qt * 128 + qc * 64) * 2304 + h * 96;
  ushort* Pw = &Ps[w][0];
  const float scale = 0.10206207261596575f;  // 1/sqrt(96)

#pragma unroll
  for (int mp = 0; mp < 2; ++mp) {
    const int qb = mp * 32;
    const int p1A = qt * 8 + qc * 4 + mp * 2;
    const int p1B = p1A + 1;

    short8 qfA[3], qfB[3];
    {
      short8 rA0 = *(const short8*)(Qp + (size_t)(qb + r16) * 2304 + 0 + kh * 8);
      short8 rA1 = *(const short8*)(Qp + (size_t)(qb + r16) * 2304 + 32 + kh * 8);
      short8 rA2 = *(const short8*)(Qp + (size_t)(qb + r16) * 2304 + 64 + kh * 8);
      short8 rB0 = *(const short8*)(Qp + (size_t)(qb + 16 + r16) * 2304 + 0 + kh * 8);
      short8 rB1 = *(const short8*)(Qp + (size_t)(qb + 16 + r16) * 2304 + 32 + kh * 8);
      short8 rB2 = *(const short8*)(Qp + (size_t)(qb + 16 + r16) * 2304 + 64 + kh * 8);
      qfA[0] = rope_frag(rA0, t0, kh, Tb);
      qfA[1] = rope_frag(rA1, p1A, kh, Tb);
      qfA[2] = rope_frag(rA2, r16, kh, Tb);
      qfB[0] = rope_frag(rB0, t0, kh, Tb);
      qfB[1] = rope_frag(rB1, p1B, kh, Tb);
      qfB[2] = rope_frag(rB2, r16, kh, Tb);
    }

    f32x4 scA[16] = {}, scB[16] = {};
#pragma unroll
    for (int f = 0; f < 16; ++f) {
#pragma unroll
      for (int kc = 0; kc < 3; ++kc) {
        short8 kf = *(const short8*)(&Ks[(f * 16 + r16) * 104 + kc * 32 + kh * 8]);
        scA[f] = __builtin_amdgcn_mfma_f32_16x16x32_bf16(qfA[kc], kf, scA[f], 0, 0, 0);
        scB[f] = __builtin_amdgcn_mfma_f32_16x16x32_bf16(qfB[kc], kf, scB[f], 0, 0, 0);
      }
    }

#pragma unroll
    for (int f = 0; f < 16; ++f) {
      float mb = Mb[f * 16 + r16];
#pragma unroll
      for (int r = 0; r < 4; ++r) {
        scA[f][r] = scA[f][r] * scale + mb;
        scB[f][r] = scB[f][r] * scale + mb;
      }
    }

    float invA[4], invB[4];
#pragma unroll
    for (int reg = 0; reg < 4; ++reg) {
      float mxA = -3.0e38f, mxB = -3.0e38f;
#pragma unroll
      for (int f = 0; f < 16; ++f) { mxA = fmaxf(mxA, scA[f][reg]); mxB = fmaxf(mxB, scB[f][reg]); }
      for (int o = 8; o >= 1; o >>= 1) { mxA = fmaxf(mxA, __shfl_xor(mxA, o, 64)); mxB = fmaxf(mxB, __shfl_xor(mxB, o, 64)); }
      float smA = 0.f, smB = 0.f;
#pragma unroll
      for (int f = 0; f < 16; ++f) {
        float pA = __expf(scA[f][reg] - mxA);
        float pB = __expf(scB[f][reg] - mxB);
        scA[f][reg] = pA; scB[f][reg] = pB;
        smA += pA; smB += pB;
      }
      for (int o = 8; o >= 1; o >>= 1) { smA += __shfl_xor(smA, o, 64); smB += __shfl_xor(smB, o, 64); }
      invA[reg] = 1.0f / smA;
      invB[reg] = 1.0f / smB;
    }

    short8 pfA[8], pfB[8];
#pragma unroll
    for (int ck = 0; ck < 2; ++ck) {
#pragma unroll
      for (int f = 0; f < 8; ++f)
#pragma unroll
        for (int reg = 0; reg < 4; ++reg)
          Pw[(kh * 4 + reg) * 136 + f * 16 + r16] = f2b(scA[ck * 8 + f][reg]);
#pragma unroll
      for (int kc = 0; kc < 4; ++kc)
        pfA[ck * 4 + kc] = *(const short8*)(&Pw[r16 * 136 + kc * 32 + kh * 8]);
    }
#pragma unroll
    for (int ck = 0; ck < 2; ++ck) {
#pragma unroll
      for (int f = 0; f < 8; ++f)
#pragma unroll
        for (int reg = 0; reg < 4; ++reg)
          Pw[(kh * 4 + reg) * 136 + f * 16 + r16] = f2b(scB[ck * 8 + f][reg]);
#pragma unroll
      for (int kc = 0; kc < 4; ++kc)
        pfB[ck * 4 + kc] = *(const short8*)(&Pw[r16 * 136 + kc * 32 + kh * 8]);
    }

    f32x4 oA[6] = {}, oB[6] = {};
#pragma unroll
    for (int dt = 0; dt < 6; ++dt) {
#pragma unroll
      for (int kc = 0; kc < 8; ++kc) {
        short8 vf = *(const short8*)(&Vs[(dt * 16 + r16) * 264 + kc * 32 + kh * 8]);
        oA[dt] = __builtin_amdgcn_mfma_f32_16x16x32_bf16(pfA[kc], vf, oA[dt], 0, 0, 0);
        oB[dt] = __builtin_amdgcn_mfma_f32_16x16x32_bf16(pfB[kc], vf, oB[dt], 0, 0, 0);
      }
    }

    const int rbase = bt * 256 + qt * 128 + qc * 64 + qb;
#pragma unroll
    for (int dt = 0; dt < 6; ++dt)
#pragma unroll
      for (int reg = 0; reg < 4; ++reg) {
        int col = h * 96 + dt * 16 + r16;
        Out[(size_t)(rbase + kh * 4 + reg) * 1536 + col]      = f2b(oA[dt][reg] * invA[reg]);
        Out[(size_t)(rbase + 16 + kh * 4 + reg) * 1536 + col] = f2b(oB[dt][reg] * invB[reg]);
      }
  }
}

// ---------- launch ----------
extern "C" void kernel_launch(void* const* d_in, const int* in_sizes, int n_in,
                              void* d_out, int out_size, void* d_ws, size_t ws_size,
                              hipStream_t stream) {
  const float* x     = (const float*)d_in[0];   // [2][16][256][1536]
  const int* pmask   = (const int*)d_in[1];     // [32][256]
  const float* w_qkv = (const float*)d_in[2];   // [2304][1536]
  const float* w_o   = (const float*)d_in[3];   // [1536][1536]
  float* out = (float*)d_out;                   // [8192][1536] f32

  char* ws = (char*)d_ws;
  ushort* Xb  = (ushort*)(ws + 0);          // 8192x1536 bf16
  ushort* Wq  = (ushort*)(ws + 25165824);   // 2304x1536 bf16
  ushort* Wo  = (ushort*)(ws + 32243712);   // 1536x1536 bf16
  ushort* QKV = (ushort*)(ws + 36962304);   // 8192x2304 bf16
  float2* Tab = (float2*)(ws + 74711040);   // 256 x float2 rope table
  ushort* Attn = Xb;                        // reuse Xb slot after gemm1

  prep_kernel<<<18049, 256, 0, stream>>>(x, w_qkv, w_o, Xb, Wq, Wo, Tab);

  gemm11<288, 1536, ushort><<<256, 256, 0, stream>>>(Xb, Wq, QKV);

  attn3_kernel<<<256, 512, 0, stream>>>(QKV, pmask, Tab, Attn);

  gemm11<192, 1536, float><<<256, 256, 0, stream>>>(Attn, Wo, out);
}

// Round 15
// 147.462 us; speedup vs baseline: 2.5121x; 2.5121x over previous
//
#include <hip/hip_runtime.h>
#include <hip/hip_bf16.h>
#include <stdint.h>

// ---------- common types / helpers ----------
typedef __attribute__((ext_vector_type(8))) short short8;   // 8 bf16 = 4 VGPR (MFMA A/B frag)
typedef __attribute__((ext_vector_type(4))) float f32x4;    // MFMA C/D frag
typedef __attribute__((ext_vector_type(4))) float f4;
typedef __attribute__((ext_vector_type(4))) short s4;

typedef __attribute__((address_space(1))) const void gvoid_t;
typedef __attribute__((address_space(3))) void lvoid_t;

__device__ __forceinline__ void gload_lds16(const void* g, void* l) {
  __builtin_amdgcn_global_load_lds((gvoid_t*)g, (lvoid_t*)l, 16, 0, 0);
}

__device__ __forceinline__ ushort f2b(float f) {  // f32 -> bf16 RNE
  union { float f; uint32_t u; } v; v.f = f;
  return (ushort)((v.u + 0x7fffu + ((v.u >> 16) & 1u)) >> 16);
}
__device__ __forceinline__ float b2f(ushort b) {
  union { uint32_t u; float f; } v; v.u = ((uint32_t)b) << 16;
  return v.f;
}

template <int N> __device__ __forceinline__ void wait_vmcnt();
template <> __device__ __forceinline__ void wait_vmcnt<0>() { asm volatile("s_waitcnt vmcnt(0)" ::: "memory"); }

__device__ __forceinline__ void wait_lgkm0() {
  asm volatile("s_waitcnt lgkmcnt(0)" ::: "memory");
  __builtin_amdgcn_sched_barrier(0);   // rule #18: keep MFMA below the wait
}
__device__ __forceinline__ void barrier_fence() {
  asm volatile("s_barrier" ::: "memory");
}

// ---------- prep: f32->bf16 casts + rope cos/sin table (one launch) ----------
__global__ void prep_kernel(const float* __restrict__ x, const float* __restrict__ wq,
                            const float* __restrict__ wo,
                            ushort* __restrict__ Xb, ushort* __restrict__ Wq,
                            ushort* __restrict__ Wo, float2* __restrict__ tab) {
  int b = blockIdx.x, tid = threadIdx.x;
  const float* in; ushort* out; int i;
  if (b < 12288)      { in = x;  out = Xb; i = b * 256 + tid; }
  else if (b < 15744) { in = wq; out = Wq; i = (b - 12288) * 256 + tid; }
  else if (b < 18048) { in = wo; out = Wo; i = (b - 15744) * 256 + tid; }
  else {
    int pos = tid >> 4, fi = tid & 15;
    float inv_freq = __expf(-(float)fi * 0.5756462732485115f);  // ln(10000)/16
    float ang = (float)pos * inv_freq;
    float sn, c;
    __sincosf(ang, &sn, &c);
    tab[tid] = make_float2(c, sn);
    return;
  }
  f4 v = ((const f4*)in)[i];
  s4 o;
  o.x = (short)f2b(v.x); o.y = (short)f2b(v.y);
  o.z = (short)f2b(v.z); o.w = (short)f2b(v.w);
  ((s4*)out)[i] = o;
}

// ---------- gemm6 (best measured 8-wave structure; used for gemm1) ----------
template <int BN, typename OutT>
__global__ __launch_bounds__(512, 2) void gemm6(const ushort* __restrict__ A,
                                                const ushort* __restrict__ B,
                                                OutT* __restrict__ C,
                                                int N, int K) {
  constexpr int NF = BN / 32;
  constexpr int RB = BN / 2;
  constexpr int ABUF = 256 * 64;
  constexpr int BBUF = BN * 64;
  constexpr uint ABYTE = ABUF * 2;
  constexpr uint BBYTE = BBUF * 2;
  constexpr int BRND = BN / 64;
  constexpr int BTW = (BN % 64) / 8;

  __shared__ ushort As[2 * ABUF];
  __shared__ ushort Bs[2 * BBUF];

  const int tid = threadIdx.x;
  const int l = tid & 63, w = tid >> 6;
  const int wr = w >> 1, wc = w & 1;
  const int r16 = l & 15, kh = l >> 4;
  const int sc = (l & 7) ^ (l >> 3);
  const int srow = w * 8 + (l >> 3);

  const int xcd = blockIdx.x & 7;
  const int ii = blockIdx.x >> 3;
  const int bm = xcd * 4 + (ii & 3);
  const int bn = ii >> 2;
  const ushort* Ag = A + (size_t)bm * 256 * K;
  const ushort* Bg = B + (size_t)bn * BN * K;
  const int NT = K >> 6;

  const char* AsR = (const char*)As;
  const char* BsR = (const char*)Bs;
  const uint khsw = ((uint)kh * 16) ^ ((uint)(r16 & 7) * 16);
  const uint PA = (uint)(wr * 64 + r16) * 128 + khsw;
  const uint PB = (uint)(wc * RB + r16) * 128 + khsw;

  const ushort* ga[4];
  const ushort* gb[BRND];
  const ushort* gbt = nullptr;
#pragma unroll
  for (int i = 0; i < 4; ++i) ga[i] = Ag + (size_t)(i * 64 + srow) * K + sc * 8;
#pragma unroll
  for (int i = 0; i < BRND; ++i) gb[i] = Bg + (size_t)(i * 64 + srow) * K + sc * 8;
  if constexpr (BTW > 0) gbt = Bg + (size_t)(BRND * 64 + srow) * K + sc * 8;

#pragma unroll
  for (int i = 0; i < 4; ++i) gload_lds16(ga[i], As + i * 4096 + w * 512);
#pragma unroll
  for (int i = 0; i < BRND; ++i) gload_lds16(gb[i], Bs + i * 4096 + w * 512);
  if constexpr (BTW > 0) { if (w < BTW) gload_lds16(gbt, Bs + BRND * 4096 + w * 512); }
#pragma unroll
  for (int i = 0; i < 4; ++i) ga[i] += 64;
#pragma unroll
  for (int i = 0; i < BRND; ++i) gb[i] += 64;
  if constexpr (BTW > 0) gbt += 64;
  wait_vmcnt<0>();
  barrier_fence();

  f32x4 acc[4][NF] = {};
  short8 afr[4], bfr[NF];

  for (int u = 0; u < NT; ++u) {
    const int cur = u & 1;
    const uint aoff = cur ? ABYTE : 0u;
    const uint boff = cur ? BBYTE : 0u;
    ushort* An = As + (cur ^ 1) * ABUF;
    ushort* Bn = Bs + (cur ^ 1) * BBUF;
    const bool st = (u + 1 < NT);

    {
      const uint pa = PA + aoff, pb = PB + boff;
#pragma unroll
      for (int m = 0; m < 4; ++m) afr[m] = *(const short8*)(AsR + pa + m * 2048);
#pragma unroll
      for (int n = 0; n < NF; ++n) bfr[n] = *(const short8*)(BsR + pb + n * 2048);
    }
    if (st) {
#pragma unroll
      for (int i = 0; i < 4; ++i) gload_lds16(ga[i], An + i * 4096 + w * 512);
    }
    wait_lgkm0();
    __builtin_amdgcn_s_setprio(1);
#pragma unroll
    for (int m = 0; m < 4; ++m)
#pragma unroll
      for (int n = 0; n < NF; ++n)
        acc[m][n] = __builtin_amdgcn_mfma_f32_16x16x32_bf16(afr[m], bfr[n], acc[m][n], 0, 0, 0);
    __builtin_amdgcn_s_setprio(0);

    {
      const uint pa = (PA ^ 64u) + aoff, pb = (PB ^ 64u) + boff;
#pragma unroll
      for (int m = 0; m < 4; ++m) afr[m] = *(const short8*)(AsR + pa + m * 2048);
#pragma unroll
      for (int n = 0; n < NF; ++n) bfr[n] = *(const short8*)(BsR + pb + n * 2048);
    }
    if (st) {
#pragma unroll
      for (int i = 0; i < BRND; ++i) gload_lds16(gb[i], Bn + i * 4096 + w * 512);
      if constexpr (BTW > 0) { if (w < BTW) gload_lds16(gbt, Bn + BRND * 4096 + w * 512); }
    }
    wait_lgkm0();
    __builtin_amdgcn_s_setprio(1);
#pragma unroll
    for (int m = 0; m < 4; ++m)
#pragma unroll
      for (int n = 0; n < NF; ++n)
        acc[m][n] = __builtin_amdgcn_mfma_f32_16x16x32_bf16(afr[m], bfr[n], acc[m][n], 0, 0, 0);
    __builtin_amdgcn_s_setprio(0);

#pragma unroll
    for (int i = 0; i < 4; ++i) ga[i] += 64;
#pragma unroll
    for (int i = 0; i < BRND; ++i) gb[i] += 64;
    if constexpr (BTW > 0) gbt += 64;
    wait_vmcnt<0>();
    barrier_fence();
  }

  const int rowb = bm * 256 + wr * 64;
  const int colb = bn * BN + wc * RB;
#pragma unroll
  for (int m = 0; m < 4; ++m)
#pragma unroll
    for (int n = 0; n < NF; ++n)
#pragma unroll
      for (int r = 0; r < 4; ++r) {
        int row = rowb + m * 16 + kh * 4 + r;
        int col = colb + n * 16 + r16;
        float val = acc[m][n][r];
        if constexpr (sizeof(OutT) == 2) C[(size_t)row * N + col] = f2b(val);
        else                             C[(size_t)row * N + col] = val;
      }
}

// ---------- gemm12: BM=128, BK=64, 256 thr, 2 blocks/CU (multi-block overlap) ----------
// Same 2-ks-phase loop, XOR swizzle, 1 drain/tile as gemm6, but 4 waves,
// LDS 80KB/block -> exactly 2 resident blocks/CU (grid 512 = 2/CU tail-free).
// acc[4][6] = 96 AGPR + ~80 VGPR < 256-threshold -> 8 waves/CU resident.
template <int BN, int KC, typename OutT>
__global__ __launch_bounds__(256, 2) void gemm12(const ushort* __restrict__ A,
                                                 const ushort* __restrict__ B,
                                                 OutT* __restrict__ C) {
  constexpr int NF = BN / 32;            // 6
  constexpr int RB = BN / 2;             // 96
  constexpr int ABUF = 128 * 64;
  constexpr int BBUF = BN * 64;
  constexpr uint ABYTE = ABUF * 2;       // 16384
  constexpr uint BBYTE = BBUF * 2;       // 24576
  constexpr int ARND = 4;                // 128 rows / 32-rows-per-round
  constexpr int BRND = BN / 32;          // 6
  constexpr int NT = KC >> 6;

  __shared__ ushort As[2 * ABUF];        // 32 KB
  __shared__ ushort Bs[2 * BBUF];        // 48 KB  (total 80 KB)

  const int tid = threadIdx.x;
  const int l = tid & 63, w = tid >> 6;  // 4 waves
  const int wr = w >> 1, wc = w & 1;     // 2M x 2N (wave-tile 64 x 96)
  const int r16 = l & 15, kh = l >> 4;
  const int sc = (l & 7) ^ (l >> 3);
  const int srow = w * 8 + (l >> 3);     // 32 rows per stage round

  const int xcd = blockIdx.x & 7;
  const int ii = blockIdx.x >> 3;        // 0..63
  const int bm = xcd * 8 + (ii & 7);     // XCD owns 8 contiguous 128-row panels
  const int bn = ii >> 3;                // 0..7
  const ushort* Ag = A + (size_t)bm * 128 * KC;
  const ushort* Bg = B + (size_t)bn * BN * KC;

  const char* AsR = (const char*)As;
  const char* BsR = (const char*)Bs;
  const uint khsw = ((uint)kh * 16) ^ ((uint)(r16 & 7) * 16);
  const uint PA = (uint)(wr * 64 + r16) * 128 + khsw;
  const uint PB = (uint)(wc * RB + r16) * 128 + khsw;

  const ushort* gA = Ag + (size_t)srow * KC + sc * 8;
  const ushort* gB = Bg + (size_t)srow * KC + sc * 8;

  // prologue: stage tile 0 into buf0
#pragma unroll
  for (int i = 0; i < ARND; ++i) gload_lds16(gA + (size_t)(i * 32) * KC, As + i * 2048 + w * 512);
#pragma unroll
  for (int i = 0; i < BRND; ++i) gload_lds16(gB + (size_t)(i * 32) * KC, Bs + i * 2048 + w * 512);
  gA += 64; gB += 64;
  wait_vmcnt<0>();
  barrier_fence();

  f32x4 acc[4][NF] = {};
  short8 afr[4], bfr[NF];

  for (int u = 0; u < NT; ++u) {
    const int cur = u & 1;
    const uint aoff = cur ? ABYTE : 0u;
    const uint boff = cur ? BBYTE : 0u;
    ushort* An = As + (cur ^ 1) * ABUF;
    ushort* Bn = Bs + (cur ^ 1) * BBUF;
    const bool st = (u + 1 < NT);

    // ---- phase 0 (ks0): reads; stage A(u+1); MFMA
    {
      const uint pa = PA + aoff, pb = PB + boff;
#pragma unroll
      for (int m = 0; m < 4; ++m) afr[m] = *(const short8*)(AsR + pa + m * 2048);
#pragma unroll
      for (int n = 0; n < NF; ++n) bfr[n] = *(const short8*)(BsR + pb + n * 2048);
    }
    if (st) {
#pragma unroll
      for (int i = 0; i < ARND; ++i) gload_lds16(gA + (size_t)(i * 32) * KC, An + i * 2048 + w * 512);
    }
    wait_lgkm0();
    __builtin_amdgcn_s_setprio(1);
#pragma unroll
    for (int m = 0; m < 4; ++m)
#pragma unroll
      for (int n = 0; n < NF; ++n)
        acc[m][n] = __builtin_amdgcn_mfma_f32_16x16x32_bf16(afr[m], bfr[n], acc[m][n], 0, 0, 0);
    __builtin_amdgcn_s_setprio(0);

    // ---- phase 1 (ks1): reads; stage B(u+1); MFMA
    {
      const uint pa = (PA ^ 64u) + aoff, pb = (PB ^ 64u) + boff;
#pragma unroll
      for (int m = 0; m < 4; ++m) afr[m] = *(const short8*)(AsR + pa + m * 2048);
#pragma unroll
      for (int n = 0; n < NF; ++n) bfr[n] = *(const short8*)(BsR + pb + n * 2048);
    }
    if (st) {
#pragma unroll
      for (int i = 0; i < BRND; ++i) gload_lds16(gB + (size_t)(i * 32) * KC, Bn + i * 2048 + w * 512);
    }
    wait_lgkm0();
    __builtin_amdgcn_s_setprio(1);
#pragma unroll
    for (int m = 0; m < 4; ++m)
#pragma unroll
      for (int n = 0; n < NF; ++n)
        acc[m][n] = __builtin_amdgcn_mfma_f32_16x16x32_bf16(afr[m], bfr[n], acc[m][n], 0, 0, 0);
    __builtin_amdgcn_s_setprio(0);

    // ---- boundary
    gA += 64; gB += 64;
    wait_vmcnt<0>();
    barrier_fence();
  }

  // epilogue
  const int rowb = bm * 128 + wr * 64;
  const int colb = bn * BN + wc * RB;
#pragma unroll
  for (int m = 0; m < 4; ++m)
#pragma unroll
    for (int n = 0; n < NF; ++n)
#pragma unroll
      for (int r = 0; r < 4; ++r) {
        int row = rowb + m * 16 + kh * 4 + r;
        int col = colb + n * 16 + r16;
        float val = acc[m][n][r];
        if constexpr (sizeof(OutT) == 2) C[(size_t)row * (BN * 8) + col] = f2b(val);
        else                             C[(size_t)row * (BN * 8) + col] = val;
      }
}

// ---------- in-register Q-rope helper: pair partner is lane^32 (kh^2) ----------
__device__ __forceinline__ short8 shfl_xor32(short8 v) {
  union { short8 s; int i[4]; } a, b;
  a.s = v;
#pragma unroll
  for (int q = 0; q < 4; ++q) b.i[q] = __shfl_xor(a.i[q], 32, 64);
  return b.s;
}
__device__ __forceinline__ short8 rope_frag(short8 v, int pos, int kh, const float2* Tb) {
  short8 p = shfl_xor32(v);
  const float sgn = (kh < 2) ? -1.0f : 1.0f;
  const int ib = pos * 16 + (kh & 1) * 8;
  short8 o;
#pragma unroll
  for (int j = 0; j < 8; ++j) {
    float2 cs = Tb[ib + j];
    o[j] = (short)f2b(b2f((ushort)v[j]) * cs.x + sgn * b2f((ushort)p[j]) * cs.y);
  }
  return o;
}

// ---------- attn3: attention + fused RoPE(Q,K) + fused V-transpose ----------
__global__ __launch_bounds__(512, 1) void attn3_kernel(
    const ushort* __restrict__ QKV,  // [8192][2304] bf16
    const int* __restrict__ mask,    // [32][256]
    const float2* __restrict__ Tab,  // [16][16] float2 (cos,sin)
    ushort* __restrict__ Out) {      // [8192][1536] bf16
  __shared__ ushort Ks[256 * 104];
  __shared__ ushort Vs[96 * 264];
  __shared__ ushort Ps[8][16 * 136];
  __shared__ float Mb[256];
  __shared__ float2 Tb[256];

  const int b = blockIdx.x;
  const int qt = b & 1;
  const int g = (b >> 1) & 3;
  const int bt = b >> 3;
  const int t = threadIdx.x;
  const int l = t & 63, w = t >> 6;
  const int r16 = l & 15, kh = l >> 4;
  const int h = g * 4 + (w >> 1);
  const int qc = w & 1;
  const int t0 = bt & 15;

  if (t < 256) { Tb[t] = Tab[t]; Mb[t] = mask[bt * 256 + t] ? 0.0f : -1.0e9f; }
  __syncthreads();

  {
    const int r = t >> 1, ch = t & 1;
    const ushort* src = QKV + (size_t)(bt * 256 + r) * 2304 + 1536 + g * 96;
    const int p1 = r >> 4, p2 = r & 15;
    if (ch == 0) {
      short8 v0 = *(const short8*)(src + 0);
      short8 v1 = *(const short8*)(src + 8);
      short8 v2 = *(const short8*)(src + 16);
      short8 v3 = *(const short8*)(src + 24);
      short8 o0, o1, o2, o3;
#pragma unroll
      for (int j = 0; j < 8; ++j) {
        float2 ca = Tb[t0 * 16 + j], cb = Tb[t0 * 16 + 8 + j];
        float x1a = b2f((ushort)v0[j]), x2a = b2f((ushort)v2[j]);
        float x1b = b2f((ushort)v1[j]), x2b = b2f((ushort)v3[j]);
        o0[j] = (short)f2b(x1a * ca.x - x2a * ca.y);
        o1[j] = (short)f2b(x1b * cb.x - x2b * cb.y);
        o2[j] = (short)f2b(x1a * ca.y + x2a * ca.x);
        o3[j] = (short)f2b(x1b * cb.y + x2b * cb.x);
      }
      *(short8*)(&Ks[r * 104 + 0])  = o0;
      *(short8*)(&Ks[r * 104 + 8])  = o1;
      *(short8*)(&Ks[r * 104 + 16]) = o2;
      *(short8*)(&Ks[r * 104 + 24]) = o3;
      v0 = *(const short8*)(src + 32);
      v1 = *(const short8*)(src + 40);
      v2 = *(const short8*)(src + 48);
      v3 = *(const short8*)(src + 56);
#pragma unroll
      for (int j = 0; j < 8; ++j) {
        float2 ca = Tb[p1 * 16 + j], cb = Tb[p1 * 16 + 8 + j];
        float x1a = b2f((ushort)v0[j]), x2a = b2f((ushort)v2[j]);
        float x1b = b2f((ushort)v1[j]), x2b = b2f((ushort)v3[j]);
        o0[j] = (short)f2b(x1a * ca.x - x2a * ca.y);
        o1[j] = (short)f2b(x1b * cb.x - x2b * cb.y);
        o2[j] = (short)f2b(x1a * ca.y + x2a * ca.x);
        o3[j] = (short)f2b(x1b * cb.y + x2b * cb.x);
      }
      *(short8*)(&Ks[r * 104 + 32]) = o0;
      *(short8*)(&Ks[r * 104 + 40]) = o1;
      *(short8*)(&Ks[r * 104 + 48]) = o2;
      *(short8*)(&Ks[r * 104 + 56]) = o3;
    } else {
      short8 v0 = *(const short8*)(src + 64);
      short8 v1 = *(const short8*)(src + 72);
      short8 v2 = *(const short8*)(src + 80);
      short8 v3 = *(const short8*)(src + 88);
      short8 o0, o1, o2, o3;
#pragma unroll
      for (int j = 0; j < 8; ++j) {
        float2 ca = Tb[p2 * 16 + j], cb = Tb[p2 * 16 + 8 + j];
        float x1a = b2f((ushort)v0[j]), x2a = b2f((ushort)v2[j]);
        float x1b = b2f((ushort)v1[j]), x2b = b2f((ushort)v3[j]);
        o0[j] = (short)f2b(x1a * ca.x - x2a * ca.y);
        o1[j] = (short)f2b(x1b * cb.x - x2b * cb.y);
        o2[j] = (short)f2b(x1a * ca.y + x2a * ca.x);
        o3[j] = (short)f2b(x1b * cb.y + x2b * cb.x);
      }
      *(short8*)(&Ks[r * 104 + 64]) = o0;
      *(short8*)(&Ks[r * 104 + 72]) = o1;
      *(short8*)(&Ks[r * 104 + 80]) = o2;
      *(short8*)(&Ks[r * 104 + 88]) = o3;
    }
  }

#pragma unroll
  for (int i = 0; i < 6; ++i) {
    int c = t + i * 512;
    int s = c / 12, dq = c - s * 12;
    short8 vv = *(const short8*)(QKV + (size_t)(bt * 256 + s) * 2304 + 1920 + g * 96 + dq * 8);
#pragma unroll
    for (int j = 0; j < 8; ++j)
      Vs[(dq * 8 + j) * 264 + s] = (ushort)vv[j];
  }
  __syncthreads();

  const ushort* Qp = QKV + (size_t)(bt * 256 + qt * 128 + qc * 64) * 2304 + h * 96;
  ushort* Pw = &Ps[w][0];
  const float scale = 0.10206207261596575f;  // 1/sqrt(96)

#pragma unroll
  for (int mp = 0; mp < 2; ++mp) {
    const int qb = mp * 32;
    const int p1A = qt * 8 + qc * 4 + mp * 2;
    const int p1B = p1A + 1;

    short8 qfA[3], qfB[3];
    {
      short8 rA0 = *(const short8*)(Qp + (size_t)(qb + r16) * 2304 + 0 + kh * 8);
      short8 rA1 = *(const short8*)(Qp + (size_t)(qb + r16) * 2304 + 32 + kh * 8);
      short8 rA2 = *(const short8*)(Qp + (size_t)(qb + r16) * 2304 + 64 + kh * 8);
      short8 rB0 = *(const short8*)(Qp + (size_t)(qb + 16 + r16) * 2304 + 0 + kh * 8);
      short8 rB1 = *(const short8*)(Qp + (size_t)(qb + 16 + r16) * 2304 + 32 + kh * 8);
      short8 rB2 = *(const short8*)(Qp + (size_t)(qb + 16 + r16) * 2304 + 64 + kh * 8);
      qfA[0] = rope_frag(rA0, t0, kh, Tb);
      qfA[1] = rope_frag(rA1, p1A, kh, Tb);
      qfA[2] = rope_frag(rA2, r16, kh, Tb);
      qfB[0] = rope_frag(rB0, t0, kh, Tb);
      qfB[1] = rope_frag(rB1, p1B, kh, Tb);
      qfB[2] = rope_frag(rB2, r16, kh, Tb);
    }

    f32x4 scA[16] = {}, scB[16] = {};
#pragma unroll
    for (int f = 0; f < 16; ++f) {
#pragma unroll
      for (int kc = 0; kc < 3; ++kc) {
        short8 kf = *(const short8*)(&Ks[(f * 16 + r16) * 104 + kc * 32 + kh * 8]);
        scA[f] = __builtin_amdgcn_mfma_f32_16x16x32_bf16(qfA[kc], kf, scA[f], 0, 0, 0);
        scB[f] = __builtin_amdgcn_mfma_f32_16x16x32_bf16(qfB[kc], kf, scB[f], 0, 0, 0);
      }
    }

#pragma unroll
    for (int f = 0; f < 16; ++f) {
      float mb = Mb[f * 16 + r16];
#pragma unroll
      for (int r = 0; r < 4; ++r) {
        scA[f][r] = scA[f][r] * scale + mb;
        scB[f][r] = scB[f][r] * scale + mb;
      }
    }

    float invA[4], invB[4];
#pragma unroll
    for (int reg = 0; reg < 4; ++reg) {
      float mxA = -3.0e38f, mxB = -3.0e38f;
#pragma unroll
      for (int f = 0; f < 16; ++f) { mxA = fmaxf(mxA, scA[f][reg]); mxB = fmaxf(mxB, scB[f][reg]); }
      for (int o = 8; o >= 1; o >>= 1) { mxA = fmaxf(mxA, __shfl_xor(mxA, o, 64)); mxB = fmaxf(mxB, __shfl_xor(mxB, o, 64)); }
      float smA = 0.f, smB = 0.f;
#pragma unroll
      for (int f = 0; f < 16; ++f) {
        float pA = __expf(scA[f][reg] - mxA);
        float pB = __expf(scB[f][reg] - mxB);
        scA[f][reg] = pA; scB[f][reg] = pB;
        smA += pA; smB += pB;
      }
      for (int o = 8; o >= 1; o >>= 1) { smA += __shfl_xor(smA, o, 64); smB += __shfl_xor(smB, o, 64); }
      invA[reg] = 1.0f / smA;
      invB[reg] = 1.0f / smB;
    }

    short8 pfA[8], pfB[8];
#pragma unroll
    for (int ck = 0; ck < 2; ++ck) {
#pragma unroll
      for (int f = 0; f < 8; ++f)
#pragma unroll
        for (int reg = 0; reg < 4; ++reg)
          Pw[(kh * 4 + reg) * 136 + f * 16 + r16] = f2b(scA[ck * 8 + f][reg]);
#pragma unroll
      for (int kc = 0; kc < 4; ++kc)
        pfA[ck * 4 + kc] = *(const short8*)(&Pw[r16 * 136 + kc * 32 + kh * 8]);
    }
#pragma unroll
    for (int ck = 0; ck < 2; ++ck) {
#pragma unroll
      for (int f = 0; f < 8; ++f)
#pragma unroll
        for (int reg = 0; reg < 4; ++reg)
          Pw[(kh * 4 + reg) * 136 + f * 16 + r16] = f2b(scB[ck * 8 + f][reg]);
#pragma unroll
      for (int kc = 0; kc < 4; ++kc)
        pfB[ck * 4 + kc] = *(const short8*)(&Pw[r16 * 136 + kc * 32 + kh * 8]);
    }

    f32x4 oA[6] = {}, oB[6] = {};
#pragma unroll
    for (int dt = 0; dt < 6; ++dt) {
#pragma unroll
      for (int kc = 0; kc < 8; ++kc) {
        short8 vf = *(const short8*)(&Vs[(dt * 16 + r16) * 264 + kc * 32 + kh * 8]);
        oA[dt] = __builtin_amdgcn_mfma_f32_16x16x32_bf16(pfA[kc], vf, oA[dt], 0, 0, 0);
        oB[dt] = __builtin_amdgcn_mfma_f32_16x16x32_bf16(pfB[kc], vf, oB[dt], 0, 0, 0);
      }
    }

    const int rbase = bt * 256 + qt * 128 + qc * 64 + qb;
#pragma unroll
    for (int dt = 0; dt < 6; ++dt)
#pragma unroll
      for (int reg = 0; reg < 4; ++reg) {
        int col = h * 96 + dt * 16 + r16;
        Out[(size_t)(rbase + kh * 4 + reg) * 1536 + col]      = f2b(oA[dt][reg] * invA[reg]);
        Out[(size_t)(rbase + 16 + kh * 4 + reg) * 1536 + col] = f2b(oB[dt][reg] * invB[reg]);
      }
  }
}

// ---------- launch ----------
extern "C" void kernel_launch(void* const* d_in, const int* in_sizes, int n_in,
                              void* d_out, int out_size, void* d_ws, size_t ws_size,
                              hipStream_t stream) {
  const float* x     = (const float*)d_in[0];   // [2][16][256][1536]
  const int* pmask   = (const int*)d_in[1];     // [32][256]
  const float* w_qkv = (const float*)d_in[2];   // [2304][1536]
  const float* w_o   = (const float*)d_in[3];   // [1536][1536]
  float* out = (float*)d_out;                   // [8192][1536] f32

  char* ws = (char*)d_ws;
  ushort* Xb  = (ushort*)(ws + 0);          // 8192x1536 bf16
  ushort* Wq  = (ushort*)(ws + 25165824);   // 2304x1536 bf16
  ushort* Wo  = (ushort*)(ws + 32243712);   // 1536x1536 bf16
  ushort* QKV = (ushort*)(ws + 36962304);   // 8192x2304 bf16
  float2* Tab = (float2*)(ws + 74711040);   // 256 x float2 rope table
  ushort* Attn = Xb;                        // reuse Xb slot after gemm1

  prep_kernel<<<18049, 256, 0, stream>>>(x, w_qkv, w_o, Xb, Wq, Wo, Tab);

  gemm6<288, ushort><<<256, 512, 0, stream>>>(Xb, Wq, QKV, 2304, 1536);

  attn3_kernel<<<256, 512, 0, stream>>>(QKV, pmask, Tab, Attn);

  gemm12<192, 1536, float><<<512, 256, 0, stream>>>(Attn, Wo, out);
}

// Round 16
// 144.496 us; speedup vs baseline: 2.5637x; 1.0205x over previous
//
#include <hip/hip_runtime.h>
#include <hip/hip_bf16.h>
#include <stdint.h>

// ---------- common types / helpers ----------
typedef __attribute__((ext_vector_type(8))) short short8;   // 8 bf16 = 4 VGPR (MFMA A/B frag)
typedef __attribute__((ext_vector_type(4))) float f32x4;    // MFMA C/D frag
typedef __attribute__((ext_vector_type(4))) float f4;
typedef __attribute__((ext_vector_type(4))) short s4;
typedef __attribute__((ext_vector_type(4))) uint u4;

typedef __attribute__((address_space(1))) const void gvoid_t;
typedef __attribute__((address_space(3))) void lvoid_t;

__device__ __forceinline__ void gload_lds16(const void* g, void* l) {
  __builtin_amdgcn_global_load_lds((gvoid_t*)g, (lvoid_t*)l, 16, 0, 0);
}

__device__ __forceinline__ ushort f2b(float f) {  // f32 -> bf16 RNE
  union { float f; uint32_t u; } v; v.f = f;
  return (ushort)((v.u + 0x7fffu + ((v.u >> 16) & 1u)) >> 16);
}
__device__ __forceinline__ float b2f(ushort b) {
  union { uint32_t u; float f; } v; v.u = ((uint32_t)b) << 16;
  return v.f;
}
__device__ __forceinline__ uint cvtpk(float lo, float hi) {   // 2x f32 -> packed bf16 (RNE)
  uint r;
  asm volatile("v_cvt_pk_bf16_f32 %0, %1, %2" : "=v"(r) : "v"(lo), "v"(hi));
  return r;
}

template <int N> __device__ __forceinline__ void wait_vmcnt();
template <> __device__ __forceinline__ void wait_vmcnt<0>() { asm volatile("s_waitcnt vmcnt(0)" ::: "memory"); }

__device__ __forceinline__ void wait_lgkm0() {
  asm volatile("s_waitcnt lgkmcnt(0)" ::: "memory");
  __builtin_amdgcn_sched_barrier(0);   // rule #18: keep MFMA below the wait
}
__device__ __forceinline__ void barrier_fence() {
  asm volatile("s_barrier" ::: "memory");
}

// ---------- prep2: weight f32->bf16 casts + rope cos/sin table ----------
__global__ void prep2_kernel(const float* __restrict__ wq, const float* __restrict__ wo,
                             ushort* __restrict__ Wq, ushort* __restrict__ Wo,
                             float2* __restrict__ tab) {
  int b = blockIdx.x, tid = threadIdx.x;
  const float* in; ushort* out; int i;
  if (b < 3456)      { in = wq; out = Wq; i = b * 256 + tid; }
  else if (b < 5760) { in = wo; out = Wo; i = (b - 3456) * 256 + tid; }
  else {
    int pos = tid >> 4, fi = tid & 15;
    float inv_freq = __expf(-(float)fi * 0.5756462732485115f);  // ln(10000)/16
    float ang = (float)pos * inv_freq;
    float sn, c;
    __sincosf(ang, &sn, &c);
    tab[tid] = make_float2(c, sn);
    return;
  }
  f4 v = ((const f4*)in)[i];
  s4 o;
  o.x = (short)f2b(v.x); o.y = (short)f2b(v.y);
  o.z = (short)f2b(v.z); o.w = (short)f2b(v.w);
  ((s4*)out)[i] = o;
}

// ---------- gemm6x: gemm6<288> with FUSED f32->bf16 A-staging (reads x directly) ----------
// A reg-staged: ph0 of tile u issues the 8-f32 loads for A(u+1) (latency hidden
// under MFMA-ks0 + rest of tile); ph1 converts (v_cvt_pk_bf16_f32) and
// ds_write_b128 to the SAME linear LDS bytes gload_lds would have written
// (source-swizzle sc unchanged -> read path identical). B via gload_lds as before.
__global__ __launch_bounds__(512, 2) void gemm6x(const float* __restrict__ Af,
                                                 const ushort* __restrict__ B,
                                                 ushort* __restrict__ C) {
  constexpr int BN = 288, NF = 9, RB = 144;
  constexpr int K = 1536, NT = 24;
  constexpr int ABUF = 256 * 64;
  constexpr int BBUF = BN * 64;
  constexpr uint ABYTE = ABUF * 2;
  constexpr uint BBYTE = BBUF * 2;
  constexpr int BRND = 4, BTW = 4;

  __shared__ ushort As[2 * ABUF];
  __shared__ ushort Bs[2 * BBUF];

  const int tid = threadIdx.x;
  const int l = tid & 63, w = tid >> 6;
  const int wr = w >> 1, wc = w & 1;
  const int r16 = l & 15, kh = l >> 4;
  const int sc = (l & 7) ^ (l >> 3);
  const int srow = w * 8 + (l >> 3);

  const int xcd = blockIdx.x & 7;
  const int ii = blockIdx.x >> 3;
  const int bm = xcd * 4 + (ii & 3);
  const int bn = ii >> 2;
  const float* Ag = Af + (size_t)bm * 256 * K;
  const ushort* Bg = B + (size_t)bn * BN * K;

  const char* AsR = (const char*)As;
  const char* BsR = (const char*)Bs;
  const uint khsw = ((uint)kh * 16) ^ ((uint)(r16 & 7) * 16);
  const uint PA = (uint)(wr * 64 + r16) * 128 + khsw;
  const uint PB = (uint)(wc * RB + r16) * 128 + khsw;

  // A f32 lane sources (4 row-groups of 64 rows) and B gload pointers
  const float* gaf[4];
  const ushort* gb[BRND];
  const ushort* gbt;
#pragma unroll
  for (int i = 0; i < 4; ++i) gaf[i] = Ag + (size_t)(i * 64 + srow) * K + sc * 8;
#pragma unroll
  for (int i = 0; i < BRND; ++i) gb[i] = Bg + (size_t)(i * 64 + srow) * K + sc * 8;
  gbt = Bg + (size_t)(BRND * 64 + srow) * K + sc * 8;

  const uint adst = (uint)w * 512 + (uint)l * 8;   // ushort offset of this lane's 16B

  // ---- prologue: A(0) reg-stage (load f32, cvt, ds_write) + B(0) gload
  {
    f4 p0[4], p1[4];
#pragma unroll
    for (int i = 0; i < 4; ++i) {
      p0[i] = *((const f4*)gaf[i]);
      p1[i] = *((const f4*)gaf[i] + 1);
    }
#pragma unroll
    for (int i = 0; i < 4; ++i) {
      u4 pk;
      pk.x = cvtpk(p0[i].x, p0[i].y);
      pk.y = cvtpk(p0[i].z, p0[i].w);
      pk.z = cvtpk(p1[i].x, p1[i].y);
      pk.w = cvtpk(p1[i].z, p1[i].w);
      *(u4*)(&As[i * 4096 + adst]) = pk;
    }
  }
#pragma unroll
  for (int i = 0; i < BRND; ++i) gload_lds16(gb[i], Bs + i * 4096 + w * 512);
  if (w < BTW) gload_lds16(gbt, Bs + BRND * 4096 + w * 512);
#pragma unroll
  for (int i = 0; i < BRND; ++i) gb[i] += 64;
  gbt += 64;
  wait_vmcnt<0>();
  wait_lgkm0();
  barrier_fence();

  f32x4 acc[4][NF] = {};
  short8 afr[4], bfr[NF];
  f4 a0[4], a1[4];   // in-flight f32 A for tile u+1

  for (int u = 0; u < NT; ++u) {
    const int cur = u & 1;
    const uint aoff = cur ? ABYTE : 0u;
    const uint boff = cur ? BBYTE : 0u;
    ushort* An = As + (cur ^ 1) * ABUF;
    ushort* Bn = Bs + (cur ^ 1) * BBUF;
    const bool st = (u + 1 < NT);
    const int kt1 = (u + 1) * 64;

    // ===== phase 0: frag reads ks0; issue A(u+1) f32 loads; MFMA ks0
    {
      const uint pa = PA + aoff, pb = PB + boff;
#pragma unroll
      for (int m = 0; m < 4; ++m) afr[m] = *(const short8*)(AsR + pa + m * 2048);
#pragma unroll
      for (int n = 0; n < NF; ++n) bfr[n] = *(const short8*)(BsR + pb + n * 2048);
    }
    if (st) {
#pragma unroll
      for (int i = 0; i < 4; ++i) {
        a0[i] = *((const f4*)(gaf[i] + kt1));
        a1[i] = *((const f4*)(gaf[i] + kt1) + 1);
      }
    }
    wait_lgkm0();
    __builtin_amdgcn_s_setprio(1);
#pragma unroll
    for (int m = 0; m < 4; ++m)
#pragma unroll
      for (int n = 0; n < NF; ++n)
        acc[m][n] = __builtin_amdgcn_mfma_f32_16x16x32_bf16(afr[m], bfr[n], acc[m][n], 0, 0, 0);
    __builtin_amdgcn_s_setprio(0);

    // ===== phase 1: frag reads ks1; cvt+write A(u+1); gload B(u+1); MFMA ks1
    {
      const uint pa = (PA ^ 64u) + aoff, pb = (PB ^ 64u) + boff;
#pragma unroll
      for (int m = 0; m < 4; ++m) afr[m] = *(const short8*)(AsR + pa + m * 2048);
#pragma unroll
      for (int n = 0; n < NF; ++n) bfr[n] = *(const short8*)(BsR + pb + n * 2048);
    }
    if (st) {
#pragma unroll
      for (int i = 0; i < 4; ++i) {
        u4 pk;
        pk.x = cvtpk(a0[i].x, a0[i].y);
        pk.y = cvtpk(a0[i].z, a0[i].w);
        pk.z = cvtpk(a1[i].x, a1[i].y);
        pk.w = cvtpk(a1[i].z, a1[i].w);
        *(u4*)(&An[i * 4096 + adst]) = pk;
      }
#pragma unroll
      for (int i = 0; i < BRND; ++i) gload_lds16(gb[i], Bn + i * 4096 + w * 512);
      if (w < BTW) gload_lds16(gbt, Bn + BRND * 4096 + w * 512);
#pragma unroll
      for (int i = 0; i < BRND; ++i) gb[i] += 64;
      gbt += 64;
    }
    wait_lgkm0();
    __builtin_amdgcn_s_setprio(1);
#pragma unroll
    for (int m = 0; m < 4; ++m)
#pragma unroll
      for (int n = 0; n < NF; ++n)
        acc[m][n] = __builtin_amdgcn_mfma_f32_16x16x32_bf16(afr[m], bfr[n], acc[m][n], 0, 0, 0);
    __builtin_amdgcn_s_setprio(0);

    // ===== boundary: drain B gloads (A writes drained by ph1 lgkm0), sync
    wait_vmcnt<0>();
    barrier_fence();
  }

  // epilogue: D col = lane&15, row = (lane>>4)*4 + reg
  const int rowb = bm * 256 + wr * 64;
  const int colb = bn * BN + wc * RB;
#pragma unroll
  for (int m = 0; m < 4; ++m)
#pragma unroll
    for (int n = 0; n < NF; ++n)
#pragma unroll
      for (int r = 0; r < 4; ++r) {
        int row = rowb + m * 16 + kh * 4 + r;
        int col = colb + n * 16 + r16;
        C[(size_t)row * 2304 + col] = f2b(acc[m][n][r]);
      }
}

// ---------- gemm6 (best measured; used for gemm2) ----------
template <int BN, typename OutT>
__global__ __launch_bounds__(512, 2) void gemm6(const ushort* __restrict__ A,
                                                const ushort* __restrict__ B,
                                                OutT* __restrict__ C,
                                                int N, int K) {
  constexpr int NF = BN / 32;
  constexpr int RB = BN / 2;
  constexpr int ABUF = 256 * 64;
  constexpr int BBUF = BN * 64;
  constexpr uint ABYTE = ABUF * 2;
  constexpr uint BBYTE = BBUF * 2;
  constexpr int BRND = BN / 64;
  constexpr int BTW = (BN % 64) / 8;

  __shared__ ushort As[2 * ABUF];
  __shared__ ushort Bs[2 * BBUF];

  const int tid = threadIdx.x;
  const int l = tid & 63, w = tid >> 6;
  const int wr = w >> 1, wc = w & 1;
  const int r16 = l & 15, kh = l >> 4;
  const int sc = (l & 7) ^ (l >> 3);
  const int srow = w * 8 + (l >> 3);

  const int xcd = blockIdx.x & 7;
  const int ii = blockIdx.x >> 3;
  const int bm = xcd * 4 + (ii & 3);
  const int bn = ii >> 2;
  const ushort* Ag = A + (size_t)bm * 256 * K;
  const ushort* Bg = B + (size_t)bn * BN * K;
  const int NT = K >> 6;

  const char* AsR = (const char*)As;
  const char* BsR = (const char*)Bs;
  const uint khsw = ((uint)kh * 16) ^ ((uint)(r16 & 7) * 16);
  const uint PA = (uint)(wr * 64 + r16) * 128 + khsw;
  const uint PB = (uint)(wc * RB + r16) * 128 + khsw;

  const ushort* ga[4];
  const ushort* gb[BRND];
  const ushort* gbt = nullptr;
#pragma unroll
  for (int i = 0; i < 4; ++i) ga[i] = Ag + (size_t)(i * 64 + srow) * K + sc * 8;
#pragma unroll
  for (int i = 0; i < BRND; ++i) gb[i] = Bg + (size_t)(i * 64 + srow) * K + sc * 8;
  if constexpr (BTW > 0) gbt = Bg + (size_t)(BRND * 64 + srow) * K + sc * 8;

#pragma unroll
  for (int i = 0; i < 4; ++i) gload_lds16(ga[i], As + i * 4096 + w * 512);
#pragma unroll
  for (int i = 0; i < BRND; ++i) gload_lds16(gb[i], Bs + i * 4096 + w * 512);
  if constexpr (BTW > 0) { if (w < BTW) gload_lds16(gbt, Bs + BRND * 4096 + w * 512); }
#pragma unroll
  for (int i = 0; i < 4; ++i) ga[i] += 64;
#pragma unroll
  for (int i = 0; i < BRND; ++i) gb[i] += 64;
  if constexpr (BTW > 0) gbt += 64;
  wait_vmcnt<0>();
  barrier_fence();

  f32x4 acc[4][NF] = {};
  short8 afr[4], bfr[NF];

  for (int u = 0; u < NT; ++u) {
    const int cur = u & 1;
    const uint aoff = cur ? ABYTE : 0u;
    const uint boff = cur ? BBYTE : 0u;
    ushort* An = As + (cur ^ 1) * ABUF;
    ushort* Bn = Bs + (cur ^ 1) * BBUF;
    const bool st = (u + 1 < NT);

    {
      const uint pa = PA + aoff, pb = PB + boff;
#pragma unroll
      for (int m = 0; m < 4; ++m) afr[m] = *(const short8*)(AsR + pa + m * 2048);
#pragma unroll
      for (int n = 0; n < NF; ++n) bfr[n] = *(const short8*)(BsR + pb + n * 2048);
    }
    if (st) {
#pragma unroll
      for (int i = 0; i < 4; ++i) gload_lds16(ga[i], An + i * 4096 + w * 512);
    }
    wait_lgkm0();
    __builtin_amdgcn_s_setprio(1);
#pragma unroll
    for (int m = 0; m < 4; ++m)
#pragma unroll
      for (int n = 0; n < NF; ++n)
        acc[m][n] = __builtin_amdgcn_mfma_f32_16x16x32_bf16(afr[m], bfr[n], acc[m][n], 0, 0, 0);
    __builtin_amdgcn_s_setprio(0);

    {
      const uint pa = (PA ^ 64u) + aoff, pb = (PB ^ 64u) + boff;
#pragma unroll
      for (int m = 0; m < 4; ++m) afr[m] = *(const short8*)(AsR + pa + m * 2048);
#pragma unroll
      for (int n = 0; n < NF; ++n) bfr[n] = *(const short8*)(BsR + pb + n * 2048);
    }
    if (st) {
#pragma unroll
      for (int i = 0; i < BRND; ++i) gload_lds16(gb[i], Bn + i * 4096 + w * 512);
      if constexpr (BTW > 0) { if (w < BTW) gload_lds16(gbt, Bn + BRND * 4096 + w * 512); }
    }
    wait_lgkm0();
    __builtin_amdgcn_s_setprio(1);
#pragma unroll
    for (int m = 0; m < 4; ++m)
#pragma unroll
      for (int n = 0; n < NF; ++n)
        acc[m][n] = __builtin_amdgcn_mfma_f32_16x16x32_bf16(afr[m], bfr[n], acc[m][n], 0, 0, 0);
    __builtin_amdgcn_s_setprio(0);

#pragma unroll
    for (int i = 0; i < 4; ++i) ga[i] += 64;
#pragma unroll
    for (int i = 0; i < BRND; ++i) gb[i] += 64;
    if constexpr (BTW > 0) gbt += 64;
    wait_vmcnt<0>();
    barrier_fence();
  }

  const int rowb = bm * 256 + wr * 64;
  const int colb = bn * BN + wc * RB;
#pragma unroll
  for (int m = 0; m < 4; ++m)
#pragma unroll
    for (int n = 0; n < NF; ++n)
#pragma unroll
      for (int r = 0; r < 4; ++r) {
        int row = rowb + m * 16 + kh * 4 + r;
        int col = colb + n * 16 + r16;
        float val = acc[m][n][r];
        if constexpr (sizeof(OutT) == 2) C[(size_t)row * N + col] = f2b(val);
        else                             C[(size_t)row * N + col] = val;
      }
}

// ---------- in-register Q-rope helper: pair partner is lane^32 (kh^2) ----------
__device__ __forceinline__ short8 shfl_xor32(short8 v) {
  union { short8 s; int i[4]; } a, b;
  a.s = v;
#pragma unroll
  for (int q = 0; q < 4; ++q) b.i[q] = __shfl_xor(a.i[q], 32, 64);
  return b.s;
}
__device__ __forceinline__ short8 rope_frag(short8 v, int pos, int kh, const float2* Tb) {
  short8 p = shfl_xor32(v);
  const float sgn = (kh < 2) ? -1.0f : 1.0f;
  const int ib = pos * 16 + (kh & 1) * 8;
  short8 o;
#pragma unroll
  for (int j = 0; j < 8; ++j) {
    float2 cs = Tb[ib + j];
    o[j] = (short)f2b(b2f((ushort)v[j]) * cs.x + sgn * b2f((ushort)p[j]) * cs.y);
  }
  return o;
}

// ---------- attn3: attention + fused RoPE(Q,K) + fused V-transpose ----------
__global__ __launch_bounds__(512, 1) void attn3_kernel(
    const ushort* __restrict__ QKV,  // [8192][2304] bf16
    const int* __restrict__ mask,    // [32][256]
    const float2* __restrict__ Tab,  // [16][16] float2 (cos,sin)
    ushort* __restrict__ Out) {      // [8192][1536] bf16
  __shared__ ushort Ks[256 * 104];
  __shared__ ushort Vs[96 * 264];
  __shared__ ushort Ps[8][16 * 136];
  __shared__ float Mb[256];
  __shared__ float2 Tb[256];

  const int b = blockIdx.x;
  const int qt = b & 1;
  const int g = (b >> 1) & 3;
  const int bt = b >> 3;
  const int t = threadIdx.x;
  const int l = t & 63, w = t >> 6;
  const int r16 = l & 15, kh = l >> 4;
  const int h = g * 4 + (w >> 1);
  const int qc = w & 1;
  const int t0 = bt & 15;

  if (t < 256) { Tb[t] = Tab[t]; Mb[t] = mask[bt * 256 + t] ? 0.0f : -1.0e9f; }
  __syncthreads();

  {
    const int r = t >> 1, ch = t & 1;
    const ushort* src = QKV + (size_t)(bt * 256 + r) * 2304 + 1536 + g * 96;
    const int p1 = r >> 4, p2 = r & 15;
    if (ch == 0) {
      short8 v0 = *(const short8*)(src + 0);
      short8 v1 = *(const short8*)(src + 8);
      short8 v2 = *(const short8*)(src + 16);
      short8 v3 = *(const short8*)(src + 24);
      short8 o0, o1, o2, o3;
#pragma unroll
      for (int j = 0; j < 8; ++j) {
        float2 ca = Tb[t0 * 16 + j], cb = Tb[t0 * 16 + 8 + j];
        float x1a = b2f((ushort)v0[j]), x2a = b2f((ushort)v2[j]);
        float x1b = b2f((ushort)v1[j]), x2b = b2f((ushort)v3[j]);
        o0[j] = (short)f2b(x1a * ca.x - x2a * ca.y);
        o1[j] = (short)f2b(x1b * cb.x - x2b * cb.y);
        o2[j] = (short)f2b(x1a * ca.y + x2a * ca.x);
        o3[j] = (short)f2b(x1b * cb.y + x2b * cb.x);
      }
      *(short8*)(&Ks[r * 104 + 0])  = o0;
      *(short8*)(&Ks[r * 104 + 8])  = o1;
      *(short8*)(&Ks[r * 104 + 16]) = o2;
      *(short8*)(&Ks[r * 104 + 24]) = o3;
      v0 = *(const short8*)(src + 32);
      v1 = *(const short8*)(src + 40);
      v2 = *(const short8*)(src + 48);
      v3 = *(const short8*)(src + 56);
#pragma unroll
      for (int j = 0; j < 8; ++j) {
        float2 ca = Tb[p1 * 16 + j], cb = Tb[p1 * 16 + 8 + j];
        float x1a = b2f((ushort)v0[j]), x2a = b2f((ushort)v2[j]);
        float x1b = b2f((ushort)v1[j]), x2b = b2f((ushort)v3[j]);
        o0[j] = (short)f2b(x1a * ca.x - x2a * ca.y);
        o1[j] = (short)f2b(x1b * cb.x - x2b * cb.y);
        o2[j] = (short)f2b(x1a * ca.y + x2a * ca.x);
        o3[j] = (short)f2b(x1b * cb.y + x2b * cb.x);
      }
      *(short8*)(&Ks[r * 104 + 32]) = o0;
      *(short8*)(&Ks[r * 104 + 40]) = o1;
      *(short8*)(&Ks[r * 104 + 48]) = o2;
      *(short8*)(&Ks[r * 104 + 56]) = o3;
    } else {
      short8 v0 = *(const short8*)(src + 64);
      short8 v1 = *(const short8*)(src + 72);
      short8 v2 = *(const short8*)(src + 80);
      short8 v3 = *(const short8*)(src + 88);
      short8 o0, o1, o2, o3;
#pragma unroll
      for (int j = 0; j < 8; ++j) {
        float2 ca = Tb[p2 * 16 + j], cb = Tb[p2 * 16 + 8 + j];
        float x1a = b2f((ushort)v0[j]), x2a = b2f((ushort)v2[j]);
        float x1b = b2f((ushort)v1[j]), x2b = b2f((ushort)v3[j]);
        o0[j] = (short)f2b(x1a * ca.x - x2a * ca.y);
        o1[j] = (short)f2b(x1b * cb.x - x2b * cb.y);
        o2[j] = (short)f2b(x1a * ca.y + x2a * ca.x);
        o3[j] = (short)f2b(x1b * cb.y + x2b * cb.x);
      }
      *(short8*)(&Ks[r * 104 + 64]) = o0;
      *(short8*)(&Ks[r * 104 + 72]) = o1;
      *(short8*)(&Ks[r * 104 + 80]) = o2;
      *(short8*)(&Ks[r * 104 + 88]) = o3;
    }
  }

#pragma unroll
  for (int i = 0; i < 6; ++i) {
    int c = t + i * 512;
    int s = c / 12, dq = c - s * 12;
    short8 vv = *(const short8*)(QKV + (size_t)(bt * 256 + s) * 2304 + 1920 + g * 96 + dq * 8);
#pragma unroll
    for (int j = 0; j < 8; ++j)
      Vs[(dq * 8 + j) * 264 + s] = (ushort)vv[j];
  }
  __syncthreads();

  const ushort* Qp = QKV + (size_t)(bt * 256 + qt * 128 + qc * 64) * 2304 + h * 96;
  ushort* Pw = &Ps[w][0];
  const float scale = 0.10206207261596575f;  // 1/sqrt(96)

#pragma unroll
  for (int mp = 0; mp < 2; ++mp) {
    const int qb = mp * 32;
    const int p1A = qt * 8 + qc * 4 + mp * 2;
    const int p1B = p1A + 1;

    short8 qfA[3], qfB[3];
    {
      short8 rA0 = *(const short8*)(Qp + (size_t)(qb + r16) * 2304 + 0 + kh * 8);
      short8 rA1 = *(const short8*)(Qp + (size_t)(qb + r16) * 2304 + 32 + kh * 8);
      short8 rA2 = *(const short8*)(Qp + (size_t)(qb + r16) * 2304 + 64 + kh * 8);
      short8 rB0 = *(const short8*)(Qp + (size_t)(qb + 16 + r16) * 2304 + 0 + kh * 8);
      short8 rB1 = *(const short8*)(Qp + (size_t)(qb + 16 + r16) * 2304 + 32 + kh * 8);
      short8 rB2 = *(const short8*)(Qp + (size_t)(qb + 16 + r16) * 2304 + 64 + kh * 8);
      qfA[0] = rope_frag(rA0, t0, kh, Tb);
      qfA[1] = rope_frag(rA1, p1A, kh, Tb);
      qfA[2] = rope_frag(rA2, r16, kh, Tb);
      qfB[0] = rope_frag(rB0, t0, kh, Tb);
      qfB[1] = rope_frag(rB1, p1B, kh, Tb);
      qfB[2] = rope_frag(rB2, r16, kh, Tb);
    }

    f32x4 scA[16] = {}, scB[16] = {};
#pragma unroll
    for (int f = 0; f < 16; ++f) {
#pragma unroll
      for (int kc = 0; kc < 3; ++kc) {
        short8 kf = *(const short8*)(&Ks[(f * 16 + r16) * 104 + kc * 32 + kh * 8]);
        scA[f] = __builtin_amdgcn_mfma_f32_16x16x32_bf16(qfA[kc], kf, scA[f], 0, 0, 0);
        scB[f] = __builtin_amdgcn_mfma_f32_16x16x32_bf16(qfB[kc], kf, scB[f], 0, 0, 0);
      }
    }

#pragma unroll
    for (int f = 0; f < 16; ++f) {
      float mb = Mb[f * 16 + r16];
#pragma unroll
      for (int r = 0; r < 4; ++r) {
        scA[f][r] = scA[f][r] * scale + mb;
        scB[f][r] = scB[f][r] * scale + mb;
      }
    }

    float invA[4], invB[4];
#pragma unroll
    for (int reg = 0; reg < 4; ++reg) {
      float mxA = -3.0e38f, mxB = -3.0e38f;
#pragma unroll
      for (int f = 0; f < 16; ++f) { mxA = fmaxf(mxA, scA[f][reg]); mxB = fmaxf(mxB, scB[f][reg]); }
      for (int o = 8; o >= 1; o >>= 1) { mxA = fmaxf(mxA, __shfl_xor(mxA, o, 64)); mxB = fmaxf(mxB, __shfl_xor(mxB, o, 64)); }
      float smA = 0.f, smB = 0.f;
#pragma unroll
      for (int f = 0; f < 16; ++f) {
        float pA = __expf(scA[f][reg] - mxA);
        float pB = __expf(scB[f][reg] - mxB);
        scA[f][reg] = pA; scB[f][reg] = pB;
        smA += pA; smB += pB;
      }
      for (int o = 8; o >= 1; o >>= 1) { smA += __shfl_xor(smA, o, 64); smB += __shfl_xor(smB, o, 64); }
      invA[reg] = 1.0f / smA;
      invB[reg] = 1.0f / smB;
    }

    short8 pfA[8], pfB[8];
#pragma unroll
    for (int ck = 0; ck < 2; ++ck) {
#pragma unroll
      for (int f = 0; f < 8; ++f)
#pragma unroll
        for (int reg = 0; reg < 4; ++reg)
          Pw[(kh * 4 + reg) * 136 + f * 16 + r16] = f2b(scA[ck * 8 + f][reg]);
#pragma unroll
      for (int kc = 0; kc < 4; ++kc)
        pfA[ck * 4 + kc] = *(const short8*)(&Pw[r16 * 136 + kc * 32 + kh * 8]);
    }
#pragma unroll
    for (int ck = 0; ck < 2; ++ck) {
#pragma unroll
      for (int f = 0; f < 8; ++f)
#pragma unroll
        for (int reg = 0; reg < 4; ++reg)
          Pw[(kh * 4 + reg) * 136 + f * 16 + r16] = f2b(scB[ck * 8 + f][reg]);
#pragma unroll
      for (int kc = 0; kc < 4; ++kc)
        pfB[ck * 4 + kc] = *(const short8*)(&Pw[r16 * 136 + kc * 32 + kh * 8]);
    }

    f32x4 oA[6] = {}, oB[6] = {};
#pragma unroll
    for (int dt = 0; dt < 6; ++dt) {
#pragma unroll
      for (int kc = 0; kc < 8; ++kc) {
        short8 vf = *(const short8*)(&Vs[(dt * 16 + r16) * 264 + kc * 32 + kh * 8]);
        oA[dt] = __builtin_amdgcn_mfma_f32_16x16x32_bf16(pfA[kc], vf, oA[dt], 0, 0, 0);
        oB[dt] = __builtin_amdgcn_mfma_f32_16x16x32_bf16(pfB[kc], vf, oB[dt], 0, 0, 0);
      }
    }

    const int rbase = bt * 256 + qt * 128 + qc * 64 + qb;
#pragma unroll
    for (int dt = 0; dt < 6; ++dt)
#pragma unroll
      for (int reg = 0; reg < 4; ++reg) {
        int col = h * 96 + dt * 16 + r16;
        Out[(size_t)(rbase + kh * 4 + reg) * 1536 + col]      = f2b(oA[dt][reg] * invA[reg]);
        Out[(size_t)(rbase + 16 + kh * 4 + reg) * 1536 + col] = f2b(oB[dt][reg] * invB[reg]);
      }
  }
}

// ---------- launch ----------
extern "C" void kernel_launch(void* const* d_in, const int* in_sizes, int n_in,
                              void* d_out, int out_size, void* d_ws, size_t ws_size,
                              hipStream_t stream) {
  const float* x     = (const float*)d_in[0];   // [2][16][256][1536]
  const int* pmask   = (const int*)d_in[1];     // [32][256]
  const float* w_qkv = (const float*)d_in[2];   // [2304][1536]
  const float* w_o   = (const float*)d_in[3];   // [1536][1536]
  float* out = (float*)d_out;                   // [8192][1536] f32

  char* ws = (char*)d_ws;
  ushort* Wq   = (ushort*)(ws + 0);          // 2304x1536 bf16 (7077888 B)
  ushort* Wo   = (ushort*)(ws + 7077888);    // 1536x1536 bf16 (4718592 B)
  ushort* QKV  = (ushort*)(ws + 11796480);   // 8192x2304 bf16 (37748736 B)
  float2* Tab  = (float2*)(ws + 49545216);   // 256 x float2 (2048 B)
  ushort* Attn = (ushort*)(ws + 49547264);   // 8192x1536 bf16 (25165824 B)

  prep2_kernel<<<5761, 256, 0, stream>>>(w_qkv, w_o, Wq, Wo, Tab);

  gemm6x<<<256, 512, 0, stream>>>(x, Wq, QKV);

  attn3_kernel<<<256, 512, 0, stream>>>(QKV, pmask, Tab, Attn);

  gemm6<192, float><<<256, 512, 0, stream>>>(Attn, Wo, out, 1536, 1536);
}

// Round 17
// 144.349 us; speedup vs baseline: 2.5663x; 1.0010x over previous
//
#include <hip/hip_runtime.h>
#include <hip/hip_bf16.h>
#include <stdint.h>

// ---------- common types / helpers ----------
typedef __attribute__((ext_vector_type(8))) short short8;   // 8 bf16 = 4 VGPR (MFMA A/B frag)
typedef __attribute__((ext_vector_type(4))) float f32x4;    // MFMA C/D frag
typedef __attribute__((ext_vector_type(4))) float f4;
typedef __attribute__((ext_vector_type(4))) short s4;
typedef __attribute__((ext_vector_type(4))) uint u4;

typedef __attribute__((address_space(1))) const void gvoid_t;
typedef __attribute__((address_space(3))) void lvoid_t;

__device__ __forceinline__ void gload_lds16(const void* g, void* l) {
  __builtin_amdgcn_global_load_lds((gvoid_t*)g, (lvoid_t*)l, 16, 0, 0);
}

__device__ __forceinline__ ushort f2b(float f) {  // f32 -> bf16 RNE
  union { float f; uint32_t u; } v; v.f = f;
  return (ushort)((v.u + 0x7fffu + ((v.u >> 16) & 1u)) >> 16);
}
__device__ __forceinline__ float b2f(ushort b) {
  union { uint32_t u; float f; } v; v.u = ((uint32_t)b) << 16;
  return v.f;
}
__device__ __forceinline__ uint cvtpk(float lo, float hi) {   // 2x f32 -> packed bf16 (RNE)
  uint r;
  asm volatile("v_cvt_pk_bf16_f32 %0, %1, %2" : "=v"(r) : "v"(lo), "v"(hi));
  return r;
}

template <int N> __device__ __forceinline__ void wait_vmcnt();
template <> __device__ __forceinline__ void wait_vmcnt<0>() { asm volatile("s_waitcnt vmcnt(0)" ::: "memory"); }

__device__ __forceinline__ void wait_lgkm0() {
  asm volatile("s_waitcnt lgkmcnt(0)" ::: "memory");
  __builtin_amdgcn_sched_barrier(0);   // rule #18: keep MFMA below the wait
}
__device__ __forceinline__ void barrier_fence() {
  asm volatile("s_barrier" ::: "memory");
}

// ---------- prep2: weight f32->bf16 casts + rope cos/sin table ----------
__global__ void prep2_kernel(const float* __restrict__ wq, const float* __restrict__ wo,
                             ushort* __restrict__ Wq, ushort* __restrict__ Wo,
                             float2* __restrict__ tab) {
  int b = blockIdx.x, tid = threadIdx.x;
  const float* in; ushort* out; int i;
  if (b < 3456)      { in = wq; out = Wq; i = b * 256 + tid; }
  else if (b < 5760) { in = wo; out = Wo; i = (b - 3456) * 256 + tid; }
  else {
    int pos = tid >> 4, fi = tid & 15;
    float inv_freq = __expf(-(float)fi * 0.5756462732485115f);  // ln(10000)/16
    float ang = (float)pos * inv_freq;
    float sn, c;
    __sincosf(ang, &sn, &c);
    tab[tid] = make_float2(c, sn);
    return;
  }
  f4 v = ((const f4*)in)[i];
  s4 o;
  o.x = (short)f2b(v.x); o.y = (short)f2b(v.y);
  o.z = (short)f2b(v.z); o.w = (short)f2b(v.w);
  ((s4*)out)[i] = o;
}

// ---------- gemm6x: gemm6<288> with FUSED f32->bf16 A-staging (reads x directly) ----------
// A reg-staged: ph0 of tile u issues the 8-f32 loads for A(u+1) (latency hidden
// under MFMA-ks0 + rest of tile); ph1 converts (v_cvt_pk_bf16_f32) and
// ds_write_b128 to the SAME linear LDS bytes gload_lds would have written
// (source-swizzle sc unchanged -> read path identical). B via gload_lds as before.
__global__ __launch_bounds__(512, 2) void gemm6x(const float* __restrict__ Af,
                                                 const ushort* __restrict__ B,
                                                 ushort* __restrict__ C) {
  constexpr int BN = 288, NF = 9, RB = 144;
  constexpr int K = 1536, NT = 24;
  constexpr int ABUF = 256 * 64;
  constexpr int BBUF = BN * 64;
  constexpr uint ABYTE = ABUF * 2;
  constexpr uint BBYTE = BBUF * 2;
  constexpr int BRND = 4, BTW = 4;

  __shared__ ushort As[2 * ABUF];
  __shared__ ushort Bs[2 * BBUF];

  const int tid = threadIdx.x;
  const int l = tid & 63, w = tid >> 6;
  const int wr = w >> 1, wc = w & 1;
  const int r16 = l & 15, kh = l >> 4;
  const int sc = (l & 7) ^ (l >> 3);
  const int srow = w * 8 + (l >> 3);

  const int xcd = blockIdx.x & 7;
  const int ii = blockIdx.x >> 3;
  const int bm = xcd * 4 + (ii & 3);
  const int bn = ii >> 2;
  const float* Ag = Af + (size_t)bm * 256 * K;
  const ushort* Bg = B + (size_t)bn * BN * K;

  const char* AsR = (const char*)As;
  const char* BsR = (const char*)Bs;
  const uint khsw = ((uint)kh * 16) ^ ((uint)(r16 & 7) * 16);
  const uint PA = (uint)(wr * 64 + r16) * 128 + khsw;
  const uint PB = (uint)(wc * RB + r16) * 128 + khsw;

  // A f32 lane sources (4 row-groups of 64 rows) and B gload pointers
  const float* gaf[4];
  const ushort* gb[BRND];
  const ushort* gbt;
#pragma unroll
  for (int i = 0; i < 4; ++i) gaf[i] = Ag + (size_t)(i * 64 + srow) * K + sc * 8;
#pragma unroll
  for (int i = 0; i < BRND; ++i) gb[i] = Bg + (size_t)(i * 64 + srow) * K + sc * 8;
  gbt = Bg + (size_t)(BRND * 64 + srow) * K + sc * 8;

  const uint adst = (uint)w * 512 + (uint)l * 8;   // ushort offset of this lane's 16B

  // ---- prologue: A(0) reg-stage (load f32, cvt, ds_write) + B(0) gload
  {
    f4 p0[4], p1[4];
#pragma unroll
    for (int i = 0; i < 4; ++i) {
      p0[i] = *((const f4*)gaf[i]);
      p1[i] = *((const f4*)gaf[i] + 1);
    }
#pragma unroll
    for (int i = 0; i < 4; ++i) {
      u4 pk;
      pk.x = cvtpk(p0[i].x, p0[i].y);
      pk.y = cvtpk(p0[i].z, p0[i].w);
      pk.z = cvtpk(p1[i].x, p1[i].y);
      pk.w = cvtpk(p1[i].z, p1[i].w);
      *(u4*)(&As[i * 4096 + adst]) = pk;
    }
  }
#pragma unroll
  for (int i = 0; i < BRND; ++i) gload_lds16(gb[i], Bs + i * 4096 + w * 512);
  if (w < BTW) gload_lds16(gbt, Bs + BRND * 4096 + w * 512);
#pragma unroll
  for (int i = 0; i < BRND; ++i) gb[i] += 64;
  gbt += 64;
  wait_vmcnt<0>();
  wait_lgkm0();
  barrier_fence();

  f32x4 acc[4][NF] = {};
  short8 afr[4], bfr[NF];
  f4 a0[4], a1[4];   // in-flight f32 A for tile u+1

  for (int u = 0; u < NT; ++u) {
    const int cur = u & 1;
    const uint aoff = cur ? ABYTE : 0u;
    const uint boff = cur ? BBYTE : 0u;
    ushort* An = As + (cur ^ 1) * ABUF;
    ushort* Bn = Bs + (cur ^ 1) * BBUF;
    const bool st = (u + 1 < NT);
    const int kt1 = (u + 1) * 64;

    // ===== phase 0: frag reads ks0; issue A(u+1) f32 loads; MFMA ks0
    {
      const uint pa = PA + aoff, pb = PB + boff;
#pragma unroll
      for (int m = 0; m < 4; ++m) afr[m] = *(const short8*)(AsR + pa + m * 2048);
#pragma unroll
      for (int n = 0; n < NF; ++n) bfr[n] = *(const short8*)(BsR + pb + n * 2048);
    }
    if (st) {
#pragma unroll
      for (int i = 0; i < 4; ++i) {
        a0[i] = *((const f4*)(gaf[i] + kt1));
        a1[i] = *((const f4*)(gaf[i] + kt1) + 1);
      }
    }
    wait_lgkm0();
    __builtin_amdgcn_s_setprio(1);
#pragma unroll
    for (int m = 0; m < 4; ++m)
#pragma unroll
      for (int n = 0; n < NF; ++n)
        acc[m][n] = __builtin_amdgcn_mfma_f32_16x16x32_bf16(afr[m], bfr[n], acc[m][n], 0, 0, 0);
    __builtin_amdgcn_s_setprio(0);

    // ===== phase 1: frag reads ks1; cvt+write A(u+1); gload B(u+1); MFMA ks1
    {
      const uint pa = (PA ^ 64u) + aoff, pb = (PB ^ 64u) + boff;
#pragma unroll
      for (int m = 0; m < 4; ++m) afr[m] = *(const short8*)(AsR + pa + m * 2048);
#pragma unroll
      for (int n = 0; n < NF; ++n) bfr[n] = *(const short8*)(BsR + pb + n * 2048);
    }
    if (st) {
#pragma unroll
      for (int i = 0; i < 4; ++i) {
        u4 pk;
        pk.x = cvtpk(a0[i].x, a0[i].y);
        pk.y = cvtpk(a0[i].z, a0[i].w);
        pk.z = cvtpk(a1[i].x, a1[i].y);
        pk.w = cvtpk(a1[i].z, a1[i].w);
        *(u4*)(&An[i * 4096 + adst]) = pk;
      }
#pragma unroll
      for (int i = 0; i < BRND; ++i) gload_lds16(gb[i], Bn + i * 4096 + w * 512);
      if (w < BTW) gload_lds16(gbt, Bn + BRND * 4096 + w * 512);
#pragma unroll
      for (int i = 0; i < BRND; ++i) gb[i] += 64;
      gbt += 64;
    }
    wait_lgkm0();
    __builtin_amdgcn_s_setprio(1);
#pragma unroll
    for (int m = 0; m < 4; ++m)
#pragma unroll
      for (int n = 0; n < NF; ++n)
        acc[m][n] = __builtin_amdgcn_mfma_f32_16x16x32_bf16(afr[m], bfr[n], acc[m][n], 0, 0, 0);
    __builtin_amdgcn_s_setprio(0);

    // ===== boundary: drain B gloads (A writes drained by ph1 lgkm0), sync
    wait_vmcnt<0>();
    barrier_fence();
  }

  // epilogue: D col = lane&15, row = (lane>>4)*4 + reg
  const int rowb = bm * 256 + wr * 64;
  const int colb = bn * BN + wc * RB;
#pragma unroll
  for (int m = 0; m < 4; ++m)
#pragma unroll
    for (int n = 0; n < NF; ++n)
#pragma unroll
      for (int r = 0; r < 4; ++r) {
        int row = rowb + m * 16 + kh * 4 + r;
        int col = colb + n * 16 + r16;
        C[(size_t)row * 2304 + col] = f2b(acc[m][n][r]);
      }
}

// ---------- gemm6 (best measured; used for gemm2) ----------
template <int BN, typename OutT>
__global__ __launch_bounds__(512, 2) void gemm6(const ushort* __restrict__ A,
                                                const ushort* __restrict__ B,
                                                OutT* __restrict__ C,
                                                int N, int K) {
  constexpr int NF = BN / 32;
  constexpr int RB = BN / 2;
  constexpr int ABUF = 256 * 64;
  constexpr int BBUF = BN * 64;
  constexpr uint ABYTE = ABUF * 2;
  constexpr uint BBYTE = BBUF * 2;
  constexpr int BRND = BN / 64;
  constexpr int BTW = (BN % 64) / 8;

  __shared__ ushort As[2 * ABUF];
  __shared__ ushort Bs[2 * BBUF];

  const int tid = threadIdx.x;
  const int l = tid & 63, w = tid >> 6;
  const int wr = w >> 1, wc = w & 1;
  const int r16 = l & 15, kh = l >> 4;
  const int sc = (l & 7) ^ (l >> 3);
  const int srow = w * 8 + (l >> 3);

  const int xcd = blockIdx.x & 7;
  const int ii = blockIdx.x >> 3;
  const int bm = xcd * 4 + (ii & 3);
  const int bn = ii >> 2;
  const ushort* Ag = A + (size_t)bm * 256 * K;
  const ushort* Bg = B + (size_t)bn * BN * K;
  const int NT = K >> 6;

  const char* AsR = (const char*)As;
  const char* BsR = (const char*)Bs;
  const uint khsw = ((uint)kh * 16) ^ ((uint)(r16 & 7) * 16);
  const uint PA = (uint)(wr * 64 + r16) * 128 + khsw;
  const uint PB = (uint)(wc * RB + r16) * 128 + khsw;

  const ushort* ga[4];
  const ushort* gb[BRND];
  const ushort* gbt = nullptr;
#pragma unroll
  for (int i = 0; i < 4; ++i) ga[i] = Ag + (size_t)(i * 64 + srow) * K + sc * 8;
#pragma unroll
  for (int i = 0; i < BRND; ++i) gb[i] = Bg + (size_t)(i * 64 + srow) * K + sc * 8;
  if constexpr (BTW > 0) gbt = Bg + (size_t)(BRND * 64 + srow) * K + sc * 8;

#pragma unroll
  for (int i = 0; i < 4; ++i) gload_lds16(ga[i], As + i * 4096 + w * 512);
#pragma unroll
  for (int i = 0; i < BRND; ++i) gload_lds16(gb[i], Bs + i * 4096 + w * 512);
  if constexpr (BTW > 0) { if (w < BTW) gload_lds16(gbt, Bs + BRND * 4096 + w * 512); }
#pragma unroll
  for (int i = 0; i < 4; ++i) ga[i] += 64;
#pragma unroll
  for (int i = 0; i < BRND; ++i) gb[i] += 64;
  if constexpr (BTW > 0) gbt += 64;
  wait_vmcnt<0>();
  barrier_fence();

  f32x4 acc[4][NF] = {};
  short8 afr[4], bfr[NF];

  for (int u = 0; u < NT; ++u) {
    const int cur = u & 1;
    const uint aoff = cur ? ABYTE : 0u;
    const uint boff = cur ? BBYTE : 0u;
    ushort* An = As + (cur ^ 1) * ABUF;
    ushort* Bn = Bs + (cur ^ 1) * BBUF;
    const bool st = (u + 1 < NT);

    {
      const uint pa = PA + aoff, pb = PB + boff;
#pragma unroll
      for (int m = 0; m < 4; ++m) afr[m] = *(const short8*)(AsR + pa + m * 2048);
#pragma unroll
      for (int n = 0; n < NF; ++n) bfr[n] = *(const short8*)(BsR + pb + n * 2048);
    }
    if (st) {
#pragma unroll
      for (int i = 0; i < 4; ++i) gload_lds16(ga[i], An + i * 4096 + w * 512);
    }
    wait_lgkm0();
    __builtin_amdgcn_s_setprio(1);
#pragma unroll
    for (int m = 0; m < 4; ++m)
#pragma unroll
      for (int n = 0; n < NF; ++n)
        acc[m][n] = __builtin_amdgcn_mfma_f32_16x16x32_bf16(afr[m], bfr[n], acc[m][n], 0, 0, 0);
    __builtin_amdgcn_s_setprio(0);

    {
      const uint pa = (PA ^ 64u) + aoff, pb = (PB ^ 64u) + boff;
#pragma unroll
      for (int m = 0; m < 4; ++m) afr[m] = *(const short8*)(AsR + pa + m * 2048);
#pragma unroll
      for (int n = 0; n < NF; ++n) bfr[n] = *(const short8*)(BsR + pb + n * 2048);
    }
    if (st) {
#pragma unroll
      for (int i = 0; i < BRND; ++i) gload_lds16(gb[i], Bn + i * 4096 + w * 512);
      if constexpr (BTW > 0) { if (w < BTW) gload_lds16(gbt, Bn + BRND * 4096 + w * 512); }
    }
    wait_lgkm0();
    __builtin_amdgcn_s_setprio(1);
#pragma unroll
    for (int m = 0; m < 4; ++m)
#pragma unroll
      for (int n = 0; n < NF; ++n)
        acc[m][n] = __builtin_amdgcn_mfma_f32_16x16x32_bf16(afr[m], bfr[n], acc[m][n], 0, 0, 0);
    __builtin_amdgcn_s_setprio(0);

#pragma unroll
    for (int i = 0; i < 4; ++i) ga[i] += 64;
#pragma unroll
    for (int i = 0; i < BRND; ++i) gb[i] += 64;
    if constexpr (BTW > 0) gbt += 64;
    wait_vmcnt<0>();
    barrier_fence();
  }

  const int rowb = bm * 256 + wr * 64;
  const int colb = bn * BN + wc * RB;
#pragma unroll
  for (int m = 0; m < 4; ++m)
#pragma unroll
    for (int n = 0; n < NF; ++n)
#pragma unroll
      for (int r = 0; r < 4; ++r) {
        int row = rowb + m * 16 + kh * 4 + r;
        int col = colb + n * 16 + r16;
        float val = acc[m][n][r];
        if constexpr (sizeof(OutT) == 2) C[(size_t)row * N + col] = f2b(val);
        else                             C[(size_t)row * N + col] = val;
      }
}

// ---------- in-register Q-rope helper: pair partner is lane^32 (kh^2) ----------
__device__ __forceinline__ short8 shfl_xor32(short8 v) {
  union { short8 s; int i[4]; } a, b;
  a.s = v;
#pragma unroll
  for (int q = 0; q < 4; ++q) b.i[q] = __shfl_xor(a.i[q], 32, 64);
  return b.s;
}
__device__ __forceinline__ short8 rope_frag(short8 v, int pos, int kh, const float2* Tb) {
  short8 p = shfl_xor32(v);
  const float sgn = (kh < 2) ? -1.0f : 1.0f;
  const int ib = pos * 16 + (kh & 1) * 8;
  short8 o;
#pragma unroll
  for (int j = 0; j < 8; ++j) {
    float2 cs = Tb[ib + j];
    o[j] = (short)f2b(b2f((ushort)v[j]) * cs.x + sgn * b2f((ushort)p[j]) * cs.y);
  }
  return o;
}

// ---------- attn3: attention + fused RoPE(Q,K) + fused V-transpose ----------
__global__ __launch_bounds__(512, 1) void attn3_kernel(
    const ushort* __restrict__ QKV,  // [8192][2304] bf16
    const int* __restrict__ mask,    // [32][256]
    const float2* __restrict__ Tab,  // [16][16] float2 (cos,sin)
    ushort* __restrict__ Out) {      // [8192][1536] bf16
  __shared__ ushort Ks[256 * 104];
  __shared__ ushort Vs[96 * 264];
  __shared__ ushort Ps[8][16 * 136];
  __shared__ float Mb[256];
  __shared__ float2 Tb[256];

  const int b = blockIdx.x;
  const int qt = b & 1;
  const int g = (b >> 1) & 3;
  const int bt = b >> 3;
  const int t = threadIdx.x;
  const int l = t & 63, w = t >> 6;
  const int r16 = l & 15, kh = l >> 4;
  const int h = g * 4 + (w >> 1);
  const int qc = w & 1;
  const int t0 = bt & 15;

  if (t < 256) { Tb[t] = Tab[t]; Mb[t] = mask[bt * 256 + t] ? 0.0f : -1.0e9f; }
  __syncthreads();

  {
    const int r = t >> 1, ch = t & 1;
    const ushort* src = QKV + (size_t)(bt * 256 + r) * 2304 + 1536 + g * 96;
    const int p1 = r >> 4, p2 = r & 15;
    if (ch == 0) {
      short8 v0 = *(const short8*)(src + 0);
      short8 v1 = *(const short8*)(src + 8);
      short8 v2 = *(const short8*)(src + 16);
      short8 v3 = *(const short8*)(src + 24);
      short8 o0, o1, o2, o3;
#pragma unroll
      for (int j = 0; j < 8; ++j) {
        float2 ca = Tb[t0 * 16 + j], cb = Tb[t0 * 16 + 8 + j];
        float x1a = b2f((ushort)v0[j]), x2a = b2f((ushort)v2[j]);
        float x1b = b2f((ushort)v1[j]), x2b = b2f((ushort)v3[j]);
        o0[j] = (short)f2b(x1a * ca.x - x2a * ca.y);
        o1[j] = (short)f2b(x1b * cb.x - x2b * cb.y);
        o2[j] = (short)f2b(x1a * ca.y + x2a * ca.x);
        o3[j] = (short)f2b(x1b * cb.y + x2b * cb.x);
      }
      *(short8*)(&Ks[r * 104 + 0])  = o0;
      *(short8*)(&Ks[r * 104 + 8])  = o1;
      *(short8*)(&Ks[r * 104 + 16]) = o2;
      *(short8*)(&Ks[r * 104 + 24]) = o3;
      v0 = *(const short8*)(src + 32);
      v1 = *(const short8*)(src + 40);
      v2 = *(const short8*)(src + 48);
      v3 = *(const short8*)(src + 56);
#pragma unroll
      for (int j = 0; j < 8; ++j) {
        float2 ca = Tb[p1 * 16 + j], cb = Tb[p1 * 16 + 8 + j];
        float x1a = b2f((ushort)v0[j]), x2a = b2f((ushort)v2[j]);
        float x1b = b2f((ushort)v1[j]), x2b = b2f((ushort)v3[j]);
        o0[j] = (short)f2b(x1a * ca.x - x2a * ca.y);
        o1[j] = (short)f2b(x1b * cb.x - x2b * cb.y);
        o2[j] = (short)f2b(x1a * ca.y + x2a * ca.x);
        o3[j] = (short)f2b(x1b * cb.y + x2b * cb.x);
      }
      *(short8*)(&Ks[r * 104 + 32]) = o0;
      *(short8*)(&Ks[r * 104 + 40]) = o1;
      *(short8*)(&Ks[r * 104 + 48]) = o2;
      *(short8*)(&Ks[r * 104 + 56]) = o3;
    } else {
      short8 v0 = *(const short8*)(src + 64);
      short8 v1 = *(const short8*)(src + 72);
      short8 v2 = *(const short8*)(src + 80);
      short8 v3 = *(const short8*)(src + 88);
      short8 o0, o1, o2, o3;
#pragma unroll
      for (int j = 0; j < 8; ++j) {
        float2 ca = Tb[p2 * 16 + j], cb = Tb[p2 * 16 + 8 + j];
        float x1a = b2f((ushort)v0[j]), x2a = b2f((ushort)v2[j]);
        float x1b = b2f((ushort)v1[j]), x2b = b2f((ushort)v3[j]);
        o0[j] = (short)f2b(x1a * ca.x - x2a * ca.y);
        o1[j] = (short)f2b(x1b * cb.x - x2b * cb.y);
        o2[j] = (short)f2b(x1a * ca.y + x2a * ca.x);
        o3[j] = (short)f2b(x1b * cb.y + x2b * cb.x);
      }
      *(short8*)(&Ks[r * 104 + 64]) = o0;
      *(short8*)(&Ks[r * 104 + 72]) = o1;
      *(short8*)(&Ks[r * 104 + 80]) = o2;
      *(short8*)(&Ks[r * 104 + 88]) = o3;
    }
  }

#pragma unroll
  for (int i = 0; i < 6; ++i) {
    int c = t + i * 512;
    int s = c / 12, dq = c - s * 12;
    short8 vv = *(const short8*)(QKV + (size_t)(bt * 256 + s) * 2304 + 1920 + g * 96 + dq * 8);
#pragma unroll
    for (int j = 0; j < 8; ++j)
      Vs[(dq * 8 + j) * 264 + s] = (ushort)vv[j];
  }
  __syncthreads();

  const ushort* Qp = QKV + (size_t)(bt * 256 + qt * 128 + qc * 64) * 2304 + h * 96;
  ushort* Pw = &Ps[w][0];
  const float scale = 0.10206207261596575f;  // 1/sqrt(96)

#pragma unroll
  for (int mp = 0; mp < 2; ++mp) {
    const int qb = mp * 32;
    const int p1A = qt * 8 + qc * 4 + mp * 2;
    const int p1B = p1A + 1;

    short8 qfA[3], qfB[3];
    {
      short8 rA0 = *(const short8*)(Qp + (size_t)(qb + r16) * 2304 + 0 + kh * 8);
      short8 rA1 = *(const short8*)(Qp + (size_t)(qb + r16) * 2304 + 32 + kh * 8);
      short8 rA2 = *(const short8*)(Qp + (size_t)(qb + r16) * 2304 + 64 + kh * 8);
      short8 rB0 = *(const short8*)(Qp + (size_t)(qb + 16 + r16) * 2304 + 0 + kh * 8);
      short8 rB1 = *(const short8*)(Qp + (size_t)(qb + 16 + r16) * 2304 + 32 + kh * 8);
      short8 rB2 = *(const short8*)(Qp + (size_t)(qb + 16 + r16) * 2304 + 64 + kh * 8);
      qfA[0] = rope_frag(rA0, t0, kh, Tb);
      qfA[1] = rope_frag(rA1, p1A, kh, Tb);
      qfA[2] = rope_frag(rA2, r16, kh, Tb);
      qfB[0] = rope_frag(rB0, t0, kh, Tb);
      qfB[1] = rope_frag(rB1, p1B, kh, Tb);
      qfB[2] = rope_frag(rB2, r16, kh, Tb);
    }

    f32x4 scA[16] = {}, scB[16] = {};
#pragma unroll
    for (int f = 0; f < 16; ++f) {
#pragma unroll
      for (int kc = 0; kc < 3; ++kc) {
        short8 kf = *(const short8*)(&Ks[(f * 16 + r16) * 104 + kc * 32 + kh * 8]);
        scA[f] = __builtin_amdgcn_mfma_f32_16x16x32_bf16(qfA[kc], kf, scA[f], 0, 0, 0);
        scB[f] = __builtin_amdgcn_mfma_f32_16x16x32_bf16(qfB[kc], kf, scB[f], 0, 0, 0);
      }
    }

#pragma unroll
    for (int f = 0; f < 16; ++f) {
      float mb = Mb[f * 16 + r16];
#pragma unroll
      for (int r = 0; r < 4; ++r) {
        scA[f][r] = scA[f][r] * scale + mb;
        scB[f][r] = scB[f][r] * scale + mb;
      }
    }

    float invA[4], invB[4];
#pragma unroll
    for (int reg = 0; reg < 4; ++reg) {
      float mxA = -3.0e38f, mxB = -3.0e38f;
#pragma unroll
      for (int f = 0; f < 16; ++f) { mxA = fmaxf(mxA, scA[f][reg]); mxB = fmaxf(mxB, scB[f][reg]); }
      for (int o = 8; o >= 1; o >>= 1) { mxA = fmaxf(mxA, __shfl_xor(mxA, o, 64)); mxB = fmaxf(mxB, __shfl_xor(mxB, o, 64)); }
      float smA = 0.f, smB = 0.f;
#pragma unroll
      for (int f = 0; f < 16; ++f) {
        float pA = __expf(scA[f][reg] - mxA);
        float pB = __expf(scB[f][reg] - mxB);
        scA[f][reg] = pA; scB[f][reg] = pB;
        smA += pA; smB += pB;
      }
      for (int o = 8; o >= 1; o >>= 1) { smA += __shfl_xor(smA, o, 64); smB += __shfl_xor(smB, o, 64); }
      invA[reg] = 1.0f / smA;
      invB[reg] = 1.0f / smB;
    }

    short8 pfA[8], pfB[8];
#pragma unroll
    for (int ck = 0; ck < 2; ++ck) {
#pragma unroll
      for (int f = 0; f < 8; ++f)
#pragma unroll
        for (int reg = 0; reg < 4; ++reg)
          Pw[(kh * 4 + reg) * 136 + f * 16 + r16] = f2b(scA[ck * 8 + f][reg]);
#pragma unroll
      for (int kc = 0; kc < 4; ++kc)
        pfA[ck * 4 + kc] = *(const short8*)(&Pw[r16 * 136 + kc * 32 + kh * 8]);
    }
#pragma unroll
    for (int ck = 0; ck < 2; ++ck) {
#pragma unroll
      for (int f = 0; f < 8; ++f)
#pragma unroll
        for (int reg = 0; reg < 4; ++reg)
          Pw[(kh * 4 + reg) * 136 + f * 16 + r16] = f2b(scB[ck * 8 + f][reg]);
#pragma unroll
      for (int kc = 0; kc < 4; ++kc)
        pfB[ck * 4 + kc] = *(const short8*)(&Pw[r16 * 136 + kc * 32 + kh * 8]);
    }

    f32x4 oA[6] = {}, oB[6] = {};
#pragma unroll
    for (int dt = 0; dt < 6; ++dt) {
#pragma unroll
      for (int kc = 0; kc < 8; ++kc) {
        short8 vf = *(const short8*)(&Vs[(dt * 16 + r16) * 264 + kc * 32 + kh * 8]);
        oA[dt] = __builtin_amdgcn_mfma_f32_16x16x32_bf16(pfA[kc], vf, oA[dt], 0, 0, 0);
        oB[dt] = __builtin_amdgcn_mfma_f32_16x16x32_bf16(pfB[kc], vf, oB[dt], 0, 0, 0);
      }
    }

    const int rbase = bt * 256 + qt * 128 + qc * 64 + qb;
#pragma unroll
    for (int dt = 0; dt < 6; ++dt)
#pragma unroll
      for (int reg = 0; reg < 4; ++reg) {
        int col = h * 96 + dt * 16 + r16;
        Out[(size_t)(rbase + kh * 4 + reg) * 1536 + col]      = f2b(oA[dt][reg] * invA[reg]);
        Out[(size_t)(rbase + 16 + kh * 4 + reg) * 1536 + col] = f2b(oB[dt][reg] * invB[reg]);
      }
  }
}

// ---------- launch ----------
extern "C" void kernel_launch(void* const* d_in, const int* in_sizes, int n_in,
                              void* d_out, int out_size, void* d_ws, size_t ws_size,
                              hipStream_t stream) {
  const float* x     = (const float*)d_in[0];   // [2][16][256][1536]
  const int* pmask   = (const int*)d_in[1];     // [32][256]
  const float* w_qkv = (const float*)d_in[2];   // [2304][1536]
  const float* w_o   = (const float*)d_in[3];   // [1536][1536]
  float* out = (float*)d_out;                   // [8192][1536] f32

  char* ws = (char*)d_ws;
  ushort* Wq   = (ushort*)(ws + 0);          // 2304x1536 bf16 (7077888 B)
  ushort* Wo   = (ushort*)(ws + 7077888);    // 1536x1536 bf16 (4718592 B)
  ushort* QKV  = (ushort*)(ws + 11796480);   // 8192x2304 bf16 (37748736 B)
  float2* Tab  = (float2*)(ws + 49545216);   // 256 x float2 (2048 B)
  ushort* Attn = (ushort*)(ws + 49547264);   // 8192x1536 bf16 (25165824 B)

  prep2_kernel<<<5761, 256, 0, stream>>>(w_qkv, w_o, Wq, Wo, Tab);

  gemm6x<<<256, 512, 0, stream>>>(x, Wq, QKV);

  attn3_kernel<<<256, 512, 0, stream>>>(QKV, pmask, Tab, Attn);

  gemm6<192, float><<<256, 512, 0, stream>>>(Attn, Wo, out, 1536, 1536);
}

// Round 18
// 141.569 us; speedup vs baseline: 2.6167x; 1.0196x over previous
//
#include <hip/hip_runtime.h>
#include <hip/hip_bf16.h>
#include <stdint.h>

// ---------- common types / helpers ----------
typedef __attribute__((ext_vector_type(8))) short short8;   // 8 bf16 = 4 VGPR (MFMA A/B frag)
typedef __attribute__((ext_vector_type(4))) float f32x4;    // MFMA C/D frag
typedef __attribute__((ext_vector_type(4))) float f4;
typedef __attribute__((ext_vector_type(4))) short s4;
typedef __attribute__((ext_vector_type(4))) uint u4;

typedef __attribute__((address_space(1))) const void gvoid_t;
typedef __attribute__((address_space(3))) void lvoid_t;

__device__ __forceinline__ void gload_lds16(const void* g, void* l) {
  __builtin_amdgcn_global_load_lds((gvoid_t*)g, (lvoid_t*)l, 16, 0, 0);
}

__device__ __forceinline__ ushort f2b(float f) {  // f32 -> bf16 RNE
  union { float f; uint32_t u; } v; v.f = f;
  return (ushort)((v.u + 0x7fffu + ((v.u >> 16) & 1u)) >> 16);
}
__device__ __forceinline__ float b2f(ushort b) {
  union { uint32_t u; float f; } v; v.u = ((uint32_t)b) << 16;
  return v.f;
}
__device__ __forceinline__ uint cvtpk(float lo, float hi) {   // 2x f32 -> packed bf16 (RNE)
  uint r;
  asm volatile("v_cvt_pk_bf16_f32 %0, %1, %2" : "=v"(r) : "v"(lo), "v"(hi));
  return r;
}

template <int N> __device__ __forceinline__ void wait_vmcnt();
template <> __device__ __forceinline__ void wait_vmcnt<0>() { asm volatile("s_waitcnt vmcnt(0)" ::: "memory"); }
template <> __device__ __forceinline__ void wait_vmcnt<8>() { asm volatile("s_waitcnt vmcnt(8)" ::: "memory"); }

__device__ __forceinline__ void wait_lgkm0() {
  asm volatile("s_waitcnt lgkmcnt(0)" ::: "memory");
  __builtin_amdgcn_sched_barrier(0);   // rule #18: keep MFMA below the wait
}
__device__ __forceinline__ void barrier_fence() {
  asm volatile("s_barrier" ::: "memory");
}

// ---------- prep2: weight f32->bf16 casts + rope cos/sin table ----------
__global__ void prep2_kernel(const float* __restrict__ wq, const float* __restrict__ wo,
                             ushort* __restrict__ Wq, ushort* __restrict__ Wo,
                             float2* __restrict__ tab) {
  int b = blockIdx.x, tid = threadIdx.x;
  const float* in; ushort* out; int i;
  if (b < 3456)      { in = wq; out = Wq; i = b * 256 + tid; }
  else if (b < 5760) { in = wo; out = Wo; i = (b - 3456) * 256 + tid; }
  else {
    int pos = tid >> 4, fi = tid & 15;
    float inv_freq = __expf(-(float)fi * 0.5756462732485115f);  // ln(10000)/16
    float ang = (float)pos * inv_freq;
    float sn, c;
    __sincosf(ang, &sn, &c);
    tab[tid] = make_float2(c, sn);
    return;
  }
  f4 v = ((const f4*)in)[i];
  s4 o;
  o.x = (short)f2b(v.x); o.y = (short)f2b(v.y);
  o.z = (short)f2b(v.z); o.w = (short)f2b(v.w);
  ((s4*)out)[i] = o;
}

// ---------- gemm6x v2: fused f32->bf16 A-staging with 1.5-tile prefetch lead ----------
// a-loads for A(u+2) issue at END of ph1 of tile u (AFTER B gloads) -> boundary
// waits vmcnt(8), draining B but leaving the 8 a-loads in flight (never drain
// the prefetch). cvt+ds_write happens at ph0 of tile u+1 behind a cheap
// vmcnt(0) (loads are ~1.5 phases + boundary old). ds_writes drain via ph0's
// lgkm0; writing An at ph0 is safe (its readers finished before the barrier).
__global__ __launch_bounds__(512, 2) void gemm6x(const float* __restrict__ Af,
                                                 const ushort* __restrict__ B,
                                                 ushort* __restrict__ C) {
  constexpr int BN = 288, NF = 9, RB = 144;
  constexpr int K = 1536, NT = 24;
  constexpr int ABUF = 256 * 64;
  constexpr int BBUF = BN * 64;
  constexpr uint ABYTE = ABUF * 2;
  constexpr uint BBYTE = BBUF * 2;
  constexpr int BRND = 4, BTW = 4;

  __shared__ ushort As[2 * ABUF];
  __shared__ ushort Bs[2 * BBUF];

  const int tid = threadIdx.x;
  const int l = tid & 63, w = tid >> 6;
  const int wr = w >> 1, wc = w & 1;
  const int r16 = l & 15, kh = l >> 4;
  const int sc = (l & 7) ^ (l >> 3);
  const int srow = w * 8 + (l >> 3);

  const int xcd = blockIdx.x & 7;
  const int ii = blockIdx.x >> 3;
  const int bm = xcd * 4 + (ii & 3);
  const int bn = ii >> 2;
  const float* Ag = Af + (size_t)bm * 256 * K;
  const ushort* Bg = B + (size_t)bn * BN * K;

  const char* AsR = (const char*)As;
  const char* BsR = (const char*)Bs;
  const uint khsw = ((uint)kh * 16) ^ ((uint)(r16 & 7) * 16);
  const uint PA = (uint)(wr * 64 + r16) * 128 + khsw;
  const uint PB = (uint)(wc * RB + r16) * 128 + khsw;

  const float* gaf[4];
  const ushort* gb[BRND];
  const ushort* gbt;
#pragma unroll
  for (int i = 0; i < 4; ++i) gaf[i] = Ag + (size_t)(i * 64 + srow) * K + sc * 8;
#pragma unroll
  for (int i = 0; i < BRND; ++i) gb[i] = Bg + (size_t)(i * 64 + srow) * K + sc * 8;
  gbt = Bg + (size_t)(BRND * 64 + srow) * K + sc * 8;

  const uint adst = (uint)w * 512 + (uint)l * 8;   // ushort offset of this lane's 16B

  f4 a0[4], a1[4];   // in-flight f32 A (1.5-tile lead)

  // ---- prologue ----
  // A(0): load, drain, cvt -> buf0
#pragma unroll
  for (int i = 0; i < 4; ++i) {
    a0[i] = *((const f4*)gaf[i]);
    a1[i] = *((const f4*)gaf[i] + 1);
  }
  wait_vmcnt<0>();
#pragma unroll
  for (int i = 0; i < 4; ++i) {
    u4 pk;
    pk.x = cvtpk(a0[i].x, a0[i].y);
    pk.y = cvtpk(a0[i].z, a0[i].w);
    pk.z = cvtpk(a1[i].x, a1[i].y);
    pk.w = cvtpk(a1[i].z, a1[i].w);
    *(u4*)(&As[i * 4096 + adst]) = pk;
  }
  // B(0) gloads FIRST, then A(1) loads (so vmcnt(8) drains B, keeps A)
#pragma unroll
  for (int i = 0; i < BRND; ++i) gload_lds16(gb[i], Bs + i * 4096 + w * 512);
  if (w < BTW) gload_lds16(gbt, Bs + BRND * 4096 + w * 512);
#pragma unroll
  for (int i = 0; i < BRND; ++i) gb[i] += 64;
  gbt += 64;
#pragma unroll
  for (int i = 0; i < 4; ++i) {
    a0[i] = *((const f4*)(gaf[i] + 64));
    a1[i] = *((const f4*)(gaf[i] + 64) + 1);
  }
  wait_vmcnt<8>();   // drain B(0); keep A(1) loads in flight
  wait_lgkm0();      // drain A(0) ds_writes
  barrier_fence();

  f32x4 acc[4][NF] = {};
  short8 afr[4], bfr[NF];

  for (int u = 0; u < NT; ++u) {
    const int cur = u & 1;
    const uint aoff = cur ? ABYTE : 0u;
    const uint boff = cur ? BBYTE : 0u;
    ushort* An = As + (cur ^ 1) * ABUF;
    ushort* Bn = Bs + (cur ^ 1) * BBUF;
    const bool st1 = (u + 1 < NT);
    const bool st2 = (u + 2 < NT);
    const int kt2 = (u + 2) * 64;

    // ===== phase 0: frag reads ks0; cvt+write A(u+1) (regs ready); MFMA ks0
    {
      const uint pa = PA + aoff, pb = PB + boff;
#pragma unroll
      for (int m = 0; m < 4; ++m) afr[m] = *(const short8*)(AsR + pa + m * 2048);
#pragma unroll
      for (int n = 0; n < NF; ++n) bfr[n] = *(const short8*)(BsR + pb + n * 2048);
    }
    if (st1) {
      wait_vmcnt<0>();   // a-loads issued 1.5 phases + boundary ago: cheap
      __builtin_amdgcn_sched_barrier(0);
#pragma unroll
      for (int i = 0; i < 4; ++i) {
        u4 pk;
        pk.x = cvtpk(a0[i].x, a0[i].y);
        pk.y = cvtpk(a0[i].z, a0[i].w);
        pk.z = cvtpk(a1[i].x, a1[i].y);
        pk.w = cvtpk(a1[i].z, a1[i].w);
        *(u4*)(&An[i * 4096 + adst]) = pk;
      }
    }
    wait_lgkm0();
    __builtin_amdgcn_s_setprio(1);
#pragma unroll
    for (int m = 0; m < 4; ++m)
#pragma unroll
      for (int n = 0; n < NF; ++n)
        acc[m][n] = __builtin_amdgcn_mfma_f32_16x16x32_bf16(afr[m], bfr[n], acc[m][n], 0, 0, 0);
    __builtin_amdgcn_s_setprio(0);

    // ===== phase 1: frag reads ks1; B(u+1) gloads; A(u+2) loads LAST; MFMA ks1
    {
      const uint pa = (PA ^ 64u) + aoff, pb = (PB ^ 64u) + boff;
#pragma unroll
      for (int m = 0; m < 4; ++m) afr[m] = *(const short8*)(AsR + pa + m * 2048);
#pragma unroll
      for (int n = 0; n < NF; ++n) bfr[n] = *(const short8*)(BsR + pb + n * 2048);
    }
    if (st1) {
#pragma unroll
      for (int i = 0; i < BRND; ++i) gload_lds16(gb[i], Bn + i * 4096 + w * 512);
      if (w < BTW) gload_lds16(gbt, Bn + BRND * 4096 + w * 512);
#pragma unroll
      for (int i = 0; i < BRND; ++i) gb[i] += 64;
      gbt += 64;
    }
    if (st2) {
#pragma unroll
      for (int i = 0; i < 4; ++i) {
        a0[i] = *((const f4*)(gaf[i] + kt2));
        a1[i] = *((const f4*)(gaf[i] + kt2) + 1);
      }
    }
    wait_lgkm0();
    __builtin_amdgcn_s_setprio(1);
#pragma unroll
    for (int m = 0; m < 4; ++m)
#pragma unroll
      for (int n = 0; n < NF; ++n)
        acc[m][n] = __builtin_amdgcn_mfma_f32_16x16x32_bf16(afr[m], bfr[n], acc[m][n], 0, 0, 0);
    __builtin_amdgcn_s_setprio(0);

    // ===== boundary: drain B gloads, keep a-loads(u+2) in flight
    if (st2) wait_vmcnt<8>(); else wait_vmcnt<0>();
    barrier_fence();
  }

  // epilogue: D col = lane&15, row = (lane>>4)*4 + reg
  const int rowb = bm * 256 + wr * 64;
  const int colb = bn * BN + wc * RB;
#pragma unroll
  for (int m = 0; m < 4; ++m)
#pragma unroll
    for (int n = 0; n < NF; ++n)
#pragma unroll
      for (int r = 0; r < 4; ++r) {
        int row = rowb + m * 16 + kh * 4 + r;
        int col = colb + n * 16 + r16;
        C[(size_t)row * 2304 + col] = f2b(acc[m][n][r]);
      }
}

// ---------- gemm6 (best measured; used for gemm2) ----------
template <int BN, typename OutT>
__global__ __launch_bounds__(512, 2) void gemm6(const ushort* __restrict__ A,
                                                const ushort* __restrict__ B,
                                                OutT* __restrict__ C,
                                                int N, int K) {
  constexpr int NF = BN / 32;
  constexpr int RB = BN / 2;
  constexpr int ABUF = 256 * 64;
  constexpr int BBUF = BN * 64;
  constexpr uint ABYTE = ABUF * 2;
  constexpr uint BBYTE = BBUF * 2;
  constexpr int BRND = BN / 64;
  constexpr int BTW = (BN % 64) / 8;

  __shared__ ushort As[2 * ABUF];
  __shared__ ushort Bs[2 * BBUF];

  const int tid = threadIdx.x;
  const int l = tid & 63, w = tid >> 6;
  const int wr = w >> 1, wc = w & 1;
  const int r16 = l & 15, kh = l >> 4;
  const int sc = (l & 7) ^ (l >> 3);
  const int srow = w * 8 + (l >> 3);

  const int xcd = blockIdx.x & 7;
  const int ii = blockIdx.x >> 3;
  const int bm = xcd * 4 + (ii & 3);
  const int bn = ii >> 2;
  const ushort* Ag = A + (size_t)bm * 256 * K;
  const ushort* Bg = B + (size_t)bn * BN * K;
  const int NT = K >> 6;

  const char* AsR = (const char*)As;
  const char* BsR = (const char*)Bs;
  const uint khsw = ((uint)kh * 16) ^ ((uint)(r16 & 7) * 16);
  const uint PA = (uint)(wr * 64 + r16) * 128 + khsw;
  const uint PB = (uint)(wc * RB + r16) * 128 + khsw;

  const ushort* ga[4];
  const ushort* gb[BRND];
  const ushort* gbt = nullptr;
#pragma unroll
  for (int i = 0; i < 4; ++i) ga[i] = Ag + (size_t)(i * 64 + srow) * K + sc * 8;
#pragma unroll
  for (int i = 0; i < BRND; ++i) gb[i] = Bg + (size_t)(i * 64 + srow) * K + sc * 8;
  if constexpr (BTW > 0) gbt = Bg + (size_t)(BRND * 64 + srow) * K + sc * 8;

#pragma unroll
  for (int i = 0; i < 4; ++i) gload_lds16(ga[i], As + i * 4096 + w * 512);
#pragma unroll
  for (int i = 0; i < BRND; ++i) gload_lds16(gb[i], Bs + i * 4096 + w * 512);
  if constexpr (BTW > 0) { if (w < BTW) gload_lds16(gbt, Bs + BRND * 4096 + w * 512); }
#pragma unroll
  for (int i = 0; i < 4; ++i) ga[i] += 64;
#pragma unroll
  for (int i = 0; i < BRND; ++i) gb[i] += 64;
  if constexpr (BTW > 0) gbt += 64;
  wait_vmcnt<0>();
  barrier_fence();

  f32x4 acc[4][NF] = {};
  short8 afr[4], bfr[NF];

  for (int u = 0; u < NT; ++u) {
    const int cur = u & 1;
    const uint aoff = cur ? ABYTE : 0u;
    const uint boff = cur ? BBYTE : 0u;
    ushort* An = As + (cur ^ 1) * ABUF;
    ushort* Bn = Bs + (cur ^ 1) * BBUF;
    const bool st = (u + 1 < NT);

    {
      const uint pa = PA + aoff, pb = PB + boff;
#pragma unroll
      for (int m = 0; m < 4; ++m) afr[m] = *(const short8*)(AsR + pa + m * 2048);
#pragma unroll
      for (int n = 0; n < NF; ++n) bfr[n] = *(const short8*)(BsR + pb + n * 2048);
    }
    if (st) {
#pragma unroll
      for (int i = 0; i < 4; ++i) gload_lds16(ga[i], An + i * 4096 + w * 512);
    }
    wait_lgkm0();
    __builtin_amdgcn_s_setprio(1);
#pragma unroll
    for (int m = 0; m < 4; ++m)
#pragma unroll
      for (int n = 0; n < NF; ++n)
        acc[m][n] = __builtin_amdgcn_mfma_f32_16x16x32_bf16(afr[m], bfr[n], acc[m][n], 0, 0, 0);
    __builtin_amdgcn_s_setprio(0);

    {
      const uint pa = (PA ^ 64u) + aoff, pb = (PB ^ 64u) + boff;
#pragma unroll
      for (int m = 0; m < 4; ++m) afr[m] = *(const short8*)(AsR + pa + m * 2048);
#pragma unroll
      for (int n = 0; n < NF; ++n) bfr[n] = *(const short8*)(BsR + pb + n * 2048);
    }
    if (st) {
#pragma unroll
      for (int i = 0; i < BRND; ++i) gload_lds16(gb[i], Bn + i * 4096 + w * 512);
      if constexpr (BTW > 0) { if (w < BTW) gload_lds16(gbt, Bn + BRND * 4096 + w * 512); }
    }
    wait_lgkm0();
    __builtin_amdgcn_s_setprio(1);
#pragma unroll
    for (int m = 0; m < 4; ++m)
#pragma unroll
      for (int n = 0; n < NF; ++n)
        acc[m][n] = __builtin_amdgcn_mfma_f32_16x16x32_bf16(afr[m], bfr[n], acc[m][n], 0, 0, 0);
    __builtin_amdgcn_s_setprio(0);

#pragma unroll
    for (int i = 0; i < 4; ++i) ga[i] += 64;
#pragma unroll
    for (int i = 0; i < BRND; ++i) gb[i] += 64;
    if constexpr (BTW > 0) gbt += 64;
    wait_vmcnt<0>();
    barrier_fence();
  }

  const int rowb = bm * 256 + wr * 64;
  const int colb = bn * BN + wc * RB;
#pragma unroll
  for (int m = 0; m < 4; ++m)
#pragma unroll
    for (int n = 0; n < NF; ++n)
#pragma unroll
      for (int r = 0; r < 4; ++r) {
        int row = rowb + m * 16 + kh * 4 + r;
        int col = colb + n * 16 + r16;
        float val = acc[m][n][r];
        if constexpr (sizeof(OutT) == 2) C[(size_t)row * N + col] = f2b(val);
        else                             C[(size_t)row * N + col] = val;
      }
}

// ---------- in-register Q-rope helper: pair partner is lane^32 (kh^2) ----------
__device__ __forceinline__ short8 shfl_xor32(short8 v) {
  union { short8 s; int i[4]; } a, b;
  a.s = v;
#pragma unroll
  for (int q = 0; q < 4; ++q) b.i[q] = __shfl_xor(a.i[q], 32, 64);
  return b.s;
}
__device__ __forceinline__ short8 rope_frag(short8 v, int pos, int kh, const float2* Tb) {
  short8 p = shfl_xor32(v);
  const float sgn = (kh < 2) ? -1.0f : 1.0f;
  const int ib = pos * 16 + (kh & 1) * 8;
  short8 o;
#pragma unroll
  for (int j = 0; j < 8; ++j) {
    float2 cs = Tb[ib + j];
    o[j] = (short)f2b(b2f((ushort)v[j]) * cs.x + sgn * b2f((ushort)p[j]) * cs.y);
  }
  return o;
}

// ---------- attn3: attention + fused RoPE(Q,K) + fused V-transpose ----------
__global__ __launch_bounds__(512, 1) void attn3_kernel(
    const ushort* __restrict__ QKV,  // [8192][2304] bf16
    const int* __restrict__ mask,    // [32][256]
    const float2* __restrict__ Tab,  // [16][16] float2 (cos,sin)
    ushort* __restrict__ Out) {      // [8192][1536] bf16
  __shared__ ushort Ks[256 * 104];
  __shared__ ushort Vs[96 * 264];
  __shared__ ushort Ps[8][16 * 136];
  __shared__ float Mb[256];
  __shared__ float2 Tb[256];

  const int b = blockIdx.x;
  const int qt = b & 1;
  const int g = (b >> 1) & 3;
  const int bt = b >> 3;
  const int t = threadIdx.x;
  const int l = t & 63, w = t >> 6;
  const int r16 = l & 15, kh = l >> 4;
  const int h = g * 4 + (w >> 1);
  const int qc = w & 1;
  const int t0 = bt & 15;

  if (t < 256) { Tb[t] = Tab[t]; Mb[t] = mask[bt * 256 + t] ? 0.0f : -1.0e9f; }
  __syncthreads();

  {
    const int r = t >> 1, ch = t & 1;
    const ushort* src = QKV + (size_t)(bt * 256 + r) * 2304 + 1536 + g * 96;
    const int p1 = r >> 4, p2 = r & 15;
    if (ch == 0) {
      short8 v0 = *(const short8*)(src + 0);
      short8 v1 = *(const short8*)(src + 8);
      short8 v2 = *(const short8*)(src + 16);
      short8 v3 = *(const short8*)(src + 24);
      short8 o0, o1, o2, o3;
#pragma unroll
      for (int j = 0; j < 8; ++j) {
        float2 ca = Tb[t0 * 16 + j], cb = Tb[t0 * 16 + 8 + j];
        float x1a = b2f((ushort)v0[j]), x2a = b2f((ushort)v2[j]);
        float x1b = b2f((ushort)v1[j]), x2b = b2f((ushort)v3[j]);
        o0[j] = (short)f2b(x1a * ca.x - x2a * ca.y);
        o1[j] = (short)f2b(x1b * cb.x - x2b * cb.y);
        o2[j] = (short)f2b(x1a * ca.y + x2a * ca.x);
        o3[j] = (short)f2b(x1b * cb.y + x2b * cb.x);
      }
      *(short8*)(&Ks[r * 104 + 0])  = o0;
      *(short8*)(&Ks[r * 104 + 8])  = o1;
      *(short8*)(&Ks[r * 104 + 16]) = o2;
      *(short8*)(&Ks[r * 104 + 24]) = o3;
      v0 = *(const short8*)(src + 32);
      v1 = *(const short8*)(src + 40);
      v2 = *(const short8*)(src + 48);
      v3 = *(const short8*)(src + 56);
#pragma unroll
      for (int j = 0; j < 8; ++j) {
        float2 ca = Tb[p1 * 16 + j], cb = Tb[p1 * 16 + 8 + j];
        float x1a = b2f((ushort)v0[j]), x2a = b2f((ushort)v2[j]);
        float x1b = b2f((ushort)v1[j]), x2b = b2f((ushort)v3[j]);
        o0[j] = (short)f2b(x1a * ca.x - x2a * ca.y);
        o1[j] = (short)f2b(x1b * cb.x - x2b * cb.y);
        o2[j] = (short)f2b(x1a * ca.y + x2a * ca.x);
        o3[j] = (short)f2b(x1b * cb.y + x2b * cb.x);
      }
      *(short8*)(&Ks[r * 104 + 32]) = o0;
      *(short8*)(&Ks[r * 104 + 40]) = o1;
      *(short8*)(&Ks[r * 104 + 48]) = o2;
      *(short8*)(&Ks[r * 104 + 56]) = o3;
    } else {
      short8 v0 = *(const short8*)(src + 64);
      short8 v1 = *(const short8*)(src + 72);
      short8 v2 = *(const short8*)(src + 80);
      short8 v3 = *(const short8*)(src + 88);
      short8 o0, o1, o2, o3;
#pragma unroll
      for (int j = 0; j < 8; ++j) {
        float2 ca = Tb[p2 * 16 + j], cb = Tb[p2 * 16 + 8 + j];
        float x1a = b2f((ushort)v0[j]), x2a = b2f((ushort)v2[j]);
        float x1b = b2f((ushort)v1[j]), x2b = b2f((ushort)v3[j]);
        o0[j] = (short)f2b(x1a * ca.x - x2a * ca.y);
        o1[j] = (short)f2b(x1b * cb.x - x2b * cb.y);
        o2[j] = (short)f2b(x1a * ca.y + x2a * ca.x);
        o3[j] = (short)f2b(x1b * cb.y + x2b * cb.x);
      }
      *(short8*)(&Ks[r * 104 + 64]) = o0;
      *(short8*)(&Ks[r * 104 + 72]) = o1;
      *(short8*)(&Ks[r * 104 + 80]) = o2;
      *(short8*)(&Ks[r * 104 + 88]) = o3;
    }
  }

#pragma unroll
  for (int i = 0; i < 6; ++i) {
    int c = t + i * 512;
    int s = c / 12, dq = c - s * 12;
    short8 vv = *(const short8*)(QKV + (size_t)(bt * 256 + s) * 2304 + 1920 + g * 96 + dq * 8);
#pragma unroll
    for (int j = 0; j < 8; ++j)
      Vs[(dq * 8 + j) * 264 + s] = (ushort)vv[j];
  }
  __syncthreads();

  const ushort* Qp = QKV + (size_t)(bt * 256 + qt * 128 + qc * 64) * 2304 + h * 96;
  ushort* Pw = &Ps[w][0];
  const float scale = 0.10206207261596575f;  // 1/sqrt(96)

#pragma unroll
  for (int mp = 0; mp < 2; ++mp) {
    const int qb = mp * 32;
    const int p1A = qt * 8 + qc * 4 + mp * 2;
    const int p1B = p1A + 1;

    short8 qfA[3], qfB[3];
    {
      short8 rA0 = *(const short8*)(Qp + (size_t)(qb + r16) * 2304 + 0 + kh * 8);
      short8 rA1 = *(const short8*)(Qp + (size_t)(qb + r16) * 2304 + 32 + kh * 8);
      short8 rA2 = *(const short8*)(Qp + (size_t)(qb + r16) * 2304 + 64 + kh * 8);
      short8 rB0 = *(const short8*)(Qp + (size_t)(qb + 16 + r16) * 2304 + 0 + kh * 8);
      short8 rB1 = *(const short8*)(Qp + (size_t)(qb + 16 + r16) * 2304 + 32 + kh * 8);
      short8 rB2 = *(const short8*)(Qp + (size_t)(qb + 16 + r16) * 2304 + 64 + kh * 8);
      qfA[0] = rope_frag(rA0, t0, kh, Tb);
      qfA[1] = rope_frag(rA1, p1A, kh, Tb);
      qfA[2] = rope_frag(rA2, r16, kh, Tb);
      qfB[0] = rope_frag(rB0, t0, kh, Tb);
      qfB[1] = rope_frag(rB1, p1B, kh, Tb);
      qfB[2] = rope_frag(rB2, r16, kh, Tb);
    }

    f32x4 scA[16] = {}, scB[16] = {};
#pragma unroll
    for (int f = 0; f < 16; ++f) {
#pragma unroll
      for (int kc = 0; kc < 3; ++kc) {
        short8 kf = *(const short8*)(&Ks[(f * 16 + r16) * 104 + kc * 32 + kh * 8]);
        scA[f] = __builtin_amdgcn_mfma_f32_16x16x32_bf16(qfA[kc], kf, scA[f], 0, 0, 0);
        scB[f] = __builtin_amdgcn_mfma_f32_16x16x32_bf16(qfB[kc], kf, scB[f], 0, 0, 0);
      }
    }

#pragma unroll
    for (int f = 0; f < 16; ++f) {
      float mb = Mb[f * 16 + r16];
#pragma unroll
      for (int r = 0; r < 4; ++r) {
        scA[f][r] = scA[f][r] * scale + mb;
        scB[f][r] = scB[f][r] * scale + mb;
      }
    }

    float invA[4], invB[4];
#pragma unroll
    for (int reg = 0; reg < 4; ++reg) {
      float mxA = -3.0e38f, mxB = -3.0e38f;
#pragma unroll
      for (int f = 0; f < 16; ++f) { mxA = fmaxf(mxA, scA[f][reg]); mxB = fmaxf(mxB, scB[f][reg]); }
      for (int o = 8; o >= 1; o >>= 1) { mxA = fmaxf(mxA, __shfl_xor(mxA, o, 64)); mxB = fmaxf(mxB, __shfl_xor(mxB, o, 64)); }
      float smA = 0.f, smB = 0.f;
#pragma unroll
      for (int f = 0; f < 16; ++f) {
        float pA = __expf(scA[f][reg] - mxA);
        float pB = __expf(scB[f][reg] - mxB);
        scA[f][reg] = pA; scB[f][reg] = pB;
        smA += pA; smB += pB;
      }
      for (int o = 8; o >= 1; o >>= 1) { smA += __shfl_xor(smA, o, 64); smB += __shfl_xor(smB, o, 64); }
      invA[reg] = 1.0f / smA;
      invB[reg] = 1.0f / smB;
    }

    short8 pfA[8], pfB[8];
#pragma unroll
    for (int ck = 0; ck < 2; ++ck) {
#pragma unroll
      for (int f = 0; f < 8; ++f)
#pragma unroll
        for (int reg = 0; reg < 4; ++reg)
          Pw[(kh * 4 + reg) * 136 + f * 16 + r16] = f2b(scA[ck * 8 + f][reg]);
#pragma unroll
      for (int kc = 0; kc < 4; ++kc)
        pfA[ck * 4 + kc] = *(const short8*)(&Pw[r16 * 136 + kc * 32 + kh * 8]);
    }
#pragma unroll
    for (int ck = 0; ck < 2; ++ck) {
#pragma unroll
      for (int f = 0; f < 8; ++f)
#pragma unroll
        for (int reg = 0; reg < 4; ++reg)
          Pw[(kh * 4 + reg) * 136 + f * 16 + r16] = f2b(scB[ck * 8 + f][reg]);
#pragma unroll
      for (int kc = 0; kc < 4; ++kc)
        pfB[ck * 4 + kc] = *(const short8*)(&Pw[r16 * 136 + kc * 32 + kh * 8]);
    }

    f32x4 oA[6] = {}, oB[6] = {};
#pragma unroll
    for (int dt = 0; dt < 6; ++dt) {
#pragma unroll
      for (int kc = 0; kc < 8; ++kc) {
        short8 vf = *(const short8*)(&Vs[(dt * 16 + r16) * 264 + kc * 32 + kh * 8]);
        oA[dt] = __builtin_amdgcn_mfma_f32_16x16x32_bf16(pfA[kc], vf, oA[dt], 0, 0, 0);
        oB[dt] = __builtin_amdgcn_mfma_f32_16x16x32_bf16(pfB[kc], vf, oB[dt], 0, 0, 0);
      }
    }

    const int rbase = bt * 256 + qt * 128 + qc * 64 + qb;
#pragma unroll
    for (int dt = 0; dt < 6; ++dt)
#pragma unroll
      for (int reg = 0; reg < 4; ++reg) {
        int col = h * 96 + dt * 16 + r16;
        Out[(size_t)(rbase + kh * 4 + reg) * 1536 + col]      = f2b(oA[dt][reg] * invA[reg]);
        Out[(size_t)(rbase + 16 + kh * 4 + reg) * 1536 + col] = f2b(oB[dt][reg] * invB[reg]);
      }
  }
}

// ---------- launch ----------
extern "C" void kernel_launch(void* const* d_in, const int* in_sizes, int n_in,
                              void* d_out, int out_size, void* d_ws, size_t ws_size,
                              hipStream_t stream) {
  const float* x     = (const float*)d_in[0];   // [2][16][256][1536]
  const int* pmask   = (const int*)d_in[1];     // [32][256]
  const float* w_qkv = (const float*)d_in[2];   // [2304][1536]
  const float* w_o   = (const float*)d_in[3];   // [1536][1536]
  float* out = (float*)d_out;                   // [8192][1536] f32

  char* ws = (char*)d_ws;
  ushort* Wq   = (ushort*)(ws + 0);          // 2304x1536 bf16
  ushort* Wo   = (ushort*)(ws + 7077888);    // 1536x1536 bf16
  ushort* QKV  = (ushort*)(ws + 11796480);   // 8192x2304 bf16
  float2* Tab  = (float2*)(ws + 49545216);   // 256 x float2
  ushort* Attn = (ushort*)(ws + 49547264);   // 8192x1536 bf16

  prep2_kernel<<<5761, 256, 0, stream>>>(w_qkv, w_o, Wq, Wo, Tab);

  gemm6x<<<256, 512, 0, stream>>>(x, Wq, QKV);

  attn3_kernel<<<256, 512, 0, stream>>>(QKV, pmask, Tab, Attn);

  gemm6<192, float><<<256, 512, 0, stream>>>(Attn, Wo, out, 1536, 1536);
}